// Round 11
// baseline (1723.306 us; speedup 1.0000x reference)
//
#include <hip/hip_runtime.h>
#include <hip/hip_bf16.h>

#define N_NODES 100000
#define E_EDGES 1600000
#define FDIM 64
#define G_GRAPHS 128
#define OUTD 32
#define CAP 16        // edges cached in LDS per node in agg (== one full iteration)
#define NPB 512       // nodes per bucket (power of 2)
#define NPB_SH 9
#define KBUK ((N_NODES + NPB - 1) / NPB)   // 196 (<= 256)
#define SEB 4096      // edges per block in bucket hist/scatter
#define SEBLK ((E_EDGES + SEB - 1) / SEB)  // 391
#define GCH 16        // chunks per graph in global pooling

__device__ __forceinline__ float4 f4min(float4 a, float4 b) {
    return make_float4(fminf(a.x,b.x), fminf(a.y,b.y), fminf(a.z,b.z), fminf(a.w,b.w));
}
__device__ __forceinline__ float4 f4max(float4 a, float4 b) {
    return make_float4(fmaxf(a.x,b.x), fmaxf(a.y,b.y), fmaxf(a.z,b.z), fmaxf(a.w,b.w));
}
__device__ __forceinline__ float4 f4add(float4 a, float4 b) {
    return make_float4(a.x+b.x, a.y+b.y, a.z+b.z, a.w+b.w);
}

// ---------------- CSR build (bucketed) ----------------

__global__ __launch_bounds__(256) void bhist_kernel(const int* __restrict__ dst,
                                                    int* __restrict__ bucketCount) {
    __shared__ int h[KBUK];
    for (int i = threadIdx.x; i < KBUK; i += 256) h[i] = 0;
    __syncthreads();
    const int base = blockIdx.x * SEB;
#pragma unroll
    for (int i = 0; i < 16; ++i) {
        int e = base + i * 256 + threadIdx.x;
        if (e < E_EDGES) atomicAdd(&h[dst[e] >> NPB_SH], 1);
    }
    __syncthreads();
    for (int i = threadIdx.x; i < KBUK; i += 256)
        if (h[i]) atomicAdd(&bucketCount[i * 16], h[i]);  // line-padded
}

__global__ __launch_bounds__(256) void bscan_kernel(const int* __restrict__ bucketCount,
                                                    int* __restrict__ bucketStart,
                                                    int* __restrict__ bucketCursor,
                                                    int* __restrict__ offsets) {
    __shared__ int s[256];
    const int tid = threadIdx.x;
    int v = (tid < KBUK) ? bucketCount[tid * 16] : 0;
    s[tid] = v;
    __syncthreads();
    for (int off = 1; off < 256; off <<= 1) {
        int t = 0;
        if (tid >= off) t = s[tid - off];
        __syncthreads();
        if (tid >= off) s[tid] += t;
        __syncthreads();
    }
    int excl = s[tid] - v;
    if (tid < KBUK) { bucketStart[tid] = excl; bucketCursor[tid * 16] = excl; }
    if (tid == 0) { bucketStart[KBUK] = E_EDGES; offsets[N_NODES] = E_EDGES; }
}

__global__ __launch_bounds__(256) void bscatter_kernel(const int* __restrict__ src,
                                                       const int* __restrict__ dst,
                                                       int* __restrict__ bucketCursor,
                                                       int* __restrict__ ebuf) {
    __shared__ int h[KBUK], resbase[KBUK], lcur[KBUK];
    for (int i = threadIdx.x; i < KBUK; i += 256) { h[i] = 0; lcur[i] = 0; }
    __syncthreads();
    const int base = blockIdx.x * SEB;
#pragma unroll
    for (int i = 0; i < 16; ++i) {
        int e = base + i * 256 + threadIdx.x;
        if (e < E_EDGES) atomicAdd(&h[dst[e] >> NPB_SH], 1);
    }
    __syncthreads();
    for (int i = threadIdx.x; i < KBUK; i += 256)
        resbase[i] = h[i] ? atomicAdd(&bucketCursor[i * 16], h[i]) : 0;
    __syncthreads();
#pragma unroll
    for (int i = 0; i < 16; ++i) {
        int e = base + i * 256 + threadIdx.x;
        if (e < E_EDGES) {
            int d = dst[e];
            int b = d >> NPB_SH;
            int pos = resbase[b] + atomicAdd(&lcur[b], 1);
            ebuf[pos] = (src[e] << NPB_SH) | (d & (NPB - 1));
        }
    }
}

__global__ __launch_bounds__(256) void bsort_kernel(const int* __restrict__ ebuf,
                                                    const int* __restrict__ bucketStart,
                                                    int* __restrict__ offsets,
                                                    int* __restrict__ srcSorted) {
    __shared__ int cnt[NPB];
    __shared__ int cur[NPB];
    __shared__ int wsum[4];
    const int b = blockIdx.x;
    const int tid = threadIdx.x;
    const int ebase = bucketStart[b], eend = bucketStart[b + 1];
    const int nbase = b * NPB;
    cnt[tid] = 0; cnt[tid + 256] = 0;
    __syncthreads();
    for (int e = ebase + tid; e < eend; e += 256)
        atomicAdd(&cnt[ebuf[e] & (NPB - 1)], 1);
    __syncthreads();
    int v0 = cnt[2 * tid], v1 = cnt[2 * tid + 1];
    int s = v0 + v1;
    const int lane = tid & 63, wv = tid >> 6;
    int incl = s;
#pragma unroll
    for (int off = 1; off < 64; off <<= 1) {
        int o = __shfl_up(incl, off);
        if (lane >= off) incl += o;
    }
    if (lane == 63) wsum[wv] = incl;
    __syncthreads();
    int wpre = 0;
#pragma unroll
    for (int w = 0; w < 4; ++w) wpre += (w < wv) ? wsum[w] : 0;
    int excl = wpre + incl - s;
    cur[2 * tid] = excl; cur[2 * tid + 1] = excl + v0;
    int n0 = nbase + 2 * tid;
    if (n0 < N_NODES) offsets[n0] = ebase + excl;
    if (n0 + 1 < N_NODES) offsets[n0 + 1] = ebase + excl + v0;
    __syncthreads();
    for (int e = ebase + tid; e < eend; e += 256) {
        int u = ebuf[e];
        int pos = ebase + atomicAdd(&cur[u & (NPB - 1)], 1);
        srcSorted[pos] = u >> NPB_SH;
    }
}

// batch is sorted -> graph g starts where batch changes value. No atomics.
__global__ __launch_bounds__(256) void bound_kernel(const int* __restrict__ batch,
                                                    int* __restrict__ gstart) {
    int i = blockIdx.x * 256 + threadIdx.x;
    if (i >= N_NODES) return;
    if (i == 0) {
        gstart[batch[0]] = 0;
    } else {
        int b = batch[i], pb = batch[i - 1];
        if (b != pb) gstart[b] = i;
    }
}

// ---------------- dual linear: 4x4 register-tiled GEMM ----------------
// 256 threads = 16 node-quads (ni) x 16 feature-quads (fj). Each thread
// computes a 4-node x 4-feature tile for M (and C if DUAL) sharing h reads.
// LDS: h tile + W tiles in float4 granularity, col-swizzled with
// col ^ ((row>>2)&7) for conflict-free reads. Dynamic LDS: 48KB dual / 32KB.
// In-place safe: block stages its own 64 rows before the barrier.

template <bool DUAL>
__global__ __launch_bounds__(256) void lin_kernel(const float* __restrict__ in,
                                                  const float* __restrict__ Wm,
                                                  const float* __restrict__ bm,
                                                  const float* __restrict__ Wc,
                                                  const float* __restrict__ bc,
                                                  float* __restrict__ outM,
                                                  float* __restrict__ outC) {
    extern __shared__ float4 sh[];  // [0,1024)=h, [1024,2048)=Wm, [2048,3072)=Wc
    const int tid = threadIdx.x;
    const int base = blockIdx.x * 64;
#pragma unroll
    for (int i = 0; i < 4; ++i) {
        int j = tid + i * 256;                 // float4 index in 64x64 tile
        int row = j >> 4, col = j & 15;
        int swz = row * 16 + (col ^ ((row >> 2) & 7));
        if (base + row < N_NODES)
            sh[swz] = ((const float4*)in)[(size_t)base * 16 + j];
        sh[1024 + swz] = ((const float4*)Wm)[j];
        if (DUAL) sh[2048 + swz] = ((const float4*)Wc)[j];
    }
    __syncthreads();
    const int fj = tid & 15, ni = tid >> 4;
    float accM[4][4] = {{0}}, accC[4][4] = {{0}};
    const int hs = ni & 7;   // (row>>2)&7 for rows 4ni+r
    const int ws = fj & 7;   // (row>>2)&7 for rows 4fj+j
#pragma unroll
    for (int kk = 0; kk < 16; ++kk) {
        const int hk = kk ^ hs, wk = kk ^ ws;
        float4 h0 = sh[(4 * ni + 0) * 16 + hk];
        float4 h1 = sh[(4 * ni + 1) * 16 + hk];
        float4 h2 = sh[(4 * ni + 2) * 16 + hk];
        float4 h3 = sh[(4 * ni + 3) * 16 + hk];
#pragma unroll
        for (int j = 0; j < 4; ++j) {
            float4 wv = sh[1024 + (4 * fj + j) * 16 + wk];
            accM[0][j] += h0.x * wv.x + h0.y * wv.y + h0.z * wv.z + h0.w * wv.w;
            accM[1][j] += h1.x * wv.x + h1.y * wv.y + h1.z * wv.z + h1.w * wv.w;
            accM[2][j] += h2.x * wv.x + h2.y * wv.y + h2.z * wv.z + h2.w * wv.w;
            accM[3][j] += h3.x * wv.x + h3.y * wv.y + h3.z * wv.z + h3.w * wv.w;
            if (DUAL) {
                float4 cv = sh[2048 + (4 * fj + j) * 16 + wk];
                accC[0][j] += h0.x * cv.x + h0.y * cv.y + h0.z * cv.z + h0.w * cv.w;
                accC[1][j] += h1.x * cv.x + h1.y * cv.y + h1.z * cv.z + h1.w * cv.w;
                accC[2][j] += h2.x * cv.x + h2.y * cv.y + h2.z * cv.z + h2.w * cv.w;
                accC[3][j] += h3.x * cv.x + h3.y * cv.y + h3.z * cv.z + h3.w * cv.w;
            }
        }
    }
    float4 bm4 = *(const float4*)(bm + 4 * fj);
    float4 bc4 = DUAL ? *(const float4*)(bc + 4 * fj) : make_float4(0, 0, 0, 0);
#pragma unroll
    for (int r = 0; r < 4; ++r) {
        int node = base + 4 * ni + r;
        if (node < N_NODES) {
            float4 o = make_float4(accM[r][0] + bm4.x, accM[r][1] + bm4.y,
                                   accM[r][2] + bm4.z, accM[r][3] + bm4.w);
            *(float4*)(outM + (size_t)node * 64 + 4 * fj) = o;
            if (DUAL) {
                float4 c = make_float4(accC[r][0] + bc4.x, accC[r][1] + bc4.y,
                                       accC[r][2] + bc4.z, accC[r][3] + bc4.w);
                *(float4*)(outC + (size_t)node * 64 + 4 * fj) = c;
            }
        }
    }
}

// ---------------- per-node adaptive-relu aggregation ----------------
// wave per node; lane = (edge group g = lane>>4, feature quad fq = lane&15).
// deg>=16: iter0 branchless (all slots cached), then branchless full-16 iters,
// then one masked tail.

__global__ __launch_bounds__(256) void agg_kernel(const float* __restrict__ msg,
                                                  const int* __restrict__ offsets,
                                                  const int* __restrict__ srcSorted,
                                                  const float* __restrict__ tptr,
                                                  const float* __restrict__ Wp,
                                                  const float* __restrict__ bp,
                                                  float* __restrict__ hbuf) {
    __shared__ float4 cache[4][CAP][16];  // 16 KB
    const int w = threadIdx.x >> 6;
    const int lane = threadIdx.x & 63;
    const int g = lane >> 4;
    const int fq = lane & 15;
    const int node = blockIdx.x * 4 + w;
    if (node >= N_NODES) return;
    const int start = offsets[node], end = offsets[node + 1];
    const int deg = end - start;
    const float4* mq = (const float4*)msg + fq;  // row stride = 16 float4
    const float INF = __builtin_inff();
    float4 mn = make_float4(INF, INF, INF, INF);
    float4 mx = make_float4(-INF, -INF, -INF, -INF);
    float4 sm = make_float4(0.f, 0.f, 0.f, 0.f);

#define ACC1(v) { mn = f4min(mn, v); mx = f4max(mx, v); sm = f4add(sm, v); }

    if (deg >= 16) {
        {
            int i0 = start + g;
            int s0 = srcSorted[i0], s1 = srcSorted[i0 + 4];
            int s2 = srcSorted[i0 + 8], s3 = srcSorted[i0 + 12];
            float4 v0 = mq[(size_t)s0 * 16], v1 = mq[(size_t)s1 * 16];
            float4 v2 = mq[(size_t)s2 * 16], v3 = mq[(size_t)s3 * 16];
            cache[w][g][fq] = v0; cache[w][g + 4][fq] = v1;
            cache[w][g + 8][fq] = v2; cache[w][g + 12][fq] = v3;
            ACC1(v0) ACC1(v1) ACC1(v2) ACC1(v3)
        }
        int e = start + 16;
        for (; e + 16 <= end; e += 16) {
            int i0 = e + g;
            int s0 = srcSorted[i0], s1 = srcSorted[i0 + 4];
            int s2 = srcSorted[i0 + 8], s3 = srcSorted[i0 + 12];
            float4 v0 = mq[(size_t)s0 * 16], v1 = mq[(size_t)s1 * 16];
            float4 v2 = mq[(size_t)s2 * 16], v3 = mq[(size_t)s3 * 16];
            ACC1(v0) ACC1(v1) ACC1(v2) ACC1(v3)
        }
        if (e < end) {
            int i0 = e + g, i1 = i0 + 4, i2 = i0 + 8, i3 = i0 + 12;
            bool ok0 = i0 < end, ok1 = i1 < end, ok2 = i2 < end, ok3 = i3 < end;
            int s0 = 0, s1 = 0, s2 = 0, s3 = 0;
            if (ok0) s0 = srcSorted[i0];
            if (ok1) s1 = srcSorted[i1];
            if (ok2) s2 = srcSorted[i2];
            if (ok3) s3 = srcSorted[i3];
            float4 v0, v1, v2, v3;
            if (ok0) v0 = mq[(size_t)s0 * 16];
            if (ok1) v1 = mq[(size_t)s1 * 16];
            if (ok2) v2 = mq[(size_t)s2 * 16];
            if (ok3) v3 = mq[(size_t)s3 * 16];
            if (ok0) ACC1(v0)
            if (ok1) ACC1(v1)
            if (ok2) ACC1(v2)
            if (ok3) ACC1(v3)
        }
    } else {
        int i0 = start + g, i1 = i0 + 4, i2 = i0 + 8, i3 = i0 + 12;
        bool ok0 = i0 < end, ok1 = i1 < end, ok2 = i2 < end, ok3 = i3 < end;
        int s0 = 0, s1 = 0, s2 = 0, s3 = 0;
        if (ok0) s0 = srcSorted[i0];
        if (ok1) s1 = srcSorted[i1];
        if (ok2) s2 = srcSorted[i2];
        if (ok3) s3 = srcSorted[i3];
        float4 v0, v1, v2, v3;
        if (ok0) v0 = mq[(size_t)s0 * 16];
        if (ok1) v1 = mq[(size_t)s1 * 16];
        if (ok2) v2 = mq[(size_t)s2 * 16];
        if (ok3) v3 = mq[(size_t)s3 * 16];
        if (ok0) { cache[w][g][fq] = v0;      ACC1(v0) }
        if (ok1) { cache[w][g + 4][fq] = v1;  ACC1(v1) }
        if (ok2) { cache[w][g + 8][fq] = v2;  ACC1(v2) }
        if (ok3) { cache[w][g + 12][fq] = v3; ACC1(v3) }
    }
#pragma unroll
    for (int off = 16; off <= 32; off <<= 1) {
        mn.x = fminf(mn.x, __shfl_xor(mn.x, off)); mn.y = fminf(mn.y, __shfl_xor(mn.y, off));
        mn.z = fminf(mn.z, __shfl_xor(mn.z, off)); mn.w = fminf(mn.w, __shfl_xor(mn.w, off));
        mx.x = fmaxf(mx.x, __shfl_xor(mx.x, off)); mx.y = fmaxf(mx.y, __shfl_xor(mx.y, off));
        mx.z = fmaxf(mx.z, __shfl_xor(mx.z, off)); mx.w = fmaxf(mx.w, __shfl_xor(mx.w, off));
        sm.x += __shfl_xor(sm.x, off); sm.y += __shfl_xor(sm.y, off);
        sm.z += __shfl_xor(sm.z, off); sm.w += __shfl_xor(sm.w, off);
    }
    float4 tv = *(const float4*)(tptr + 4 * fq);
    tv.x = fminf(fmaxf(tv.x, 0.f), 1.f); tv.y = fminf(fmaxf(tv.y, 0.f), 1.f);
    tv.z = fminf(fmaxf(tv.z, 0.f), 1.f); tv.w = fminf(fmaxf(tv.w, 0.f), 1.f);
    float4 bias;
    bias.x = tv.x * mx.x + (1.f - tv.x) * mn.x;
    bias.y = tv.y * mx.y + (1.f - tv.y) * mn.y;
    bias.z = tv.z * mx.z + (1.f - tv.z) * mn.z;
    bias.w = tv.w * mx.w + (1.f - tv.w) * mn.w;
    float4 rs = make_float4(0.f, 0.f, 0.f, 0.f);

#define RACC(v) { rs.x += fmaxf(v.x - bias.x, 0.f); rs.y += fmaxf(v.y - bias.y, 0.f); \
                  rs.z += fmaxf(v.z - bias.z, 0.f); rs.w += fmaxf(v.w - bias.w, 0.f); }

    if (deg >= 16) {
#pragma unroll
        for (int i = 0; i < 4; ++i) {
            float4 v = cache[w][i * 4 + g][fq];
            RACC(v)
        }
        int e = start + 16;
        for (; e + 16 <= end; e += 16) {
            int i0 = e + g;
            int s0 = srcSorted[i0], s1 = srcSorted[i0 + 4];
            int s2 = srcSorted[i0 + 8], s3 = srcSorted[i0 + 12];
            float4 v0 = mq[(size_t)s0 * 16], v1 = mq[(size_t)s1 * 16];
            float4 v2 = mq[(size_t)s2 * 16], v3 = mq[(size_t)s3 * 16];
            RACC(v0) RACC(v1) RACC(v2) RACC(v3)
        }
        if (e < end) {
            int i0 = e + g, i1 = i0 + 4, i2 = i0 + 8, i3 = i0 + 12;
            bool ok0 = i0 < end, ok1 = i1 < end, ok2 = i2 < end, ok3 = i3 < end;
            int s0 = 0, s1 = 0, s2 = 0, s3 = 0;
            if (ok0) s0 = srcSorted[i0];
            if (ok1) s1 = srcSorted[i1];
            if (ok2) s2 = srcSorted[i2];
            if (ok3) s3 = srcSorted[i3];
            float4 v0, v1, v2, v3;
            if (ok0) v0 = mq[(size_t)s0 * 16];
            if (ok1) v1 = mq[(size_t)s1 * 16];
            if (ok2) v2 = mq[(size_t)s2 * 16];
            if (ok3) v3 = mq[(size_t)s3 * 16];
            if (ok0) RACC(v0)
            if (ok1) RACC(v1)
            if (ok2) RACC(v2)
            if (ok3) RACC(v3)
        }
    } else {
        for (int idx = start + g; idx < end; idx += 4) {
            float4 v = cache[w][idx - start][fq];
            RACC(v)
        }
    }
#pragma unroll
    for (int off = 16; off <= 32; off <<= 1) {
        rs.x += __shfl_xor(rs.x, off); rs.y += __shfl_xor(rs.y, off);
        rs.z += __shfl_xor(rs.z, off); rs.w += __shfl_xor(rs.w, off);
    }
    if (g == 0) {
        float cnt = (float)deg;
        float w0 = Wp[0], w1 = Wp[1], w2 = Wp[2], w3 = Wp[3], w4 = Wp[4], b0 = bp[0];
        float4* hp = (float4*)(hbuf + (size_t)node * 64 + 4 * fq);
        float4 h = *hp;
        h.x += w0 * cnt + w1 * mn.x + w2 * mx.x + w3 * rs.x + w4 * sm.x + b0;
        h.y += w0 * cnt + w1 * mn.y + w2 * mx.y + w3 * rs.y + w4 * sm.y + b0;
        h.z += w0 * cnt + w1 * mn.z + w2 * mx.z + w3 * rs.z + w4 * sm.z + b0;
        h.w += w0 * cnt + w1 * mn.w + w2 * mx.w + w3 * rs.w + w4 * sm.w + b0;
        *hp = h;
    }
#undef ACC1
#undef RACC
}

// ---------------- global pooling (4-phase, parallel) ----------------

__global__ __launch_bounds__(256) void gaggA_kernel(const float* __restrict__ msg,
                                                    const int* __restrict__ gstart,
                                                    float* __restrict__ pmn,
                                                    float* __restrict__ pmx,
                                                    float* __restrict__ psm) {
    const int bid = blockIdx.x;
    const int g = bid >> 4, c = bid & (GCH - 1);
    const int s = gstart[g];
    const int e = (g == G_GRAPHS - 1) ? N_NODES : gstart[g + 1];
    const int clen = (e - s + GCH - 1) / GCH;
    const int cs = s + c * clen;
    const int ce = (cs + clen < e) ? (cs + clen) : e;
    const int f = threadIdx.x & 63, r = threadIdx.x >> 6;
    float mn = __builtin_inff(), mx = -__builtin_inff(), sm = 0.f;
    for (int i = cs + r; i < ce; i += 4) {
        float v = msg[(size_t)i * 64 + f];
        mn = fminf(mn, v); mx = fmaxf(mx, v); sm += v;
    }
    __shared__ float smn[4][64], smx[4][64], ssm[4][64];
    smn[r][f] = mn; smx[r][f] = mx; ssm[r][f] = sm;
    __syncthreads();
    if (r == 0) {
        pmn[bid * 64 + f] = fminf(fminf(smn[0][f], smn[1][f]), fminf(smn[2][f], smn[3][f]));
        pmx[bid * 64 + f] = fmaxf(fmaxf(smx[0][f], smx[1][f]), fmaxf(smx[2][f], smx[3][f]));
        psm[bid * 64 + f] = ssm[0][f] + ssm[1][f] + ssm[2][f] + ssm[3][f];
    }
}

__global__ __launch_bounds__(64) void gaggB_kernel(const float* __restrict__ pmn,
                                                   const float* __restrict__ pmx,
                                                   const float* __restrict__ psm,
                                                   const float* __restrict__ gt,
                                                   float* __restrict__ gMn,
                                                   float* __restrict__ gMx,
                                                   float* __restrict__ gSm,
                                                   float* __restrict__ gBias) {
    const int g = blockIdx.x, f = threadIdx.x;
    float mn = __builtin_inff(), mx = -__builtin_inff(), sm = 0.f;
#pragma unroll
    for (int c = 0; c < GCH; ++c) {
        int i = (g * GCH + c) * 64 + f;
        mn = fminf(mn, pmn[i]); mx = fmaxf(mx, pmx[i]); sm += psm[i];
    }
    float tv = fminf(fmaxf(gt[f], 0.f), 1.f);
    gMn[g * 64 + f] = mn; gMx[g * 64 + f] = mx; gSm[g * 64 + f] = sm;
    gBias[g * 64 + f] = tv * mx + (1.f - tv) * mn;
}

__global__ __launch_bounds__(256) void gaggC_kernel(const float* __restrict__ msg,
                                                    const int* __restrict__ gstart,
                                                    const float* __restrict__ gBias,
                                                    float* __restrict__ prs) {
    const int bid = blockIdx.x;
    const int g = bid >> 4, c = bid & (GCH - 1);
    const int s = gstart[g];
    const int e = (g == G_GRAPHS - 1) ? N_NODES : gstart[g + 1];
    const int clen = (e - s + GCH - 1) / GCH;
    const int cs = s + c * clen;
    const int ce = (cs + clen < e) ? (cs + clen) : e;
    const int f = threadIdx.x & 63, r = threadIdx.x >> 6;
    const float bias = gBias[g * 64 + f];
    float rs = 0.f;
    for (int i = cs + r; i < ce; i += 4) {
        float v = msg[(size_t)i * 64 + f];
        rs += fmaxf(v - bias, 0.f);
    }
    __shared__ float srs[4][64];
    srs[r][f] = rs;
    __syncthreads();
    if (r == 0)
        prs[bid * 64 + f] = srs[0][f] + srs[1][f] + srs[2][f] + srs[3][f];
}

__global__ __launch_bounds__(64) void gaggD_kernel(const float* __restrict__ prs,
                                                   const int* __restrict__ gstart,
                                                   const float* __restrict__ gMn,
                                                   const float* __restrict__ gMx,
                                                   const float* __restrict__ gSm,
                                                   const float* __restrict__ gWp,
                                                   const float* __restrict__ gbp,
                                                   const float* __restrict__ Wout,
                                                   const float* __restrict__ bout,
                                                   float* __restrict__ out) {
    const int g = blockIdx.x, f = threadIdx.x;
    float rs = 0.f;
#pragma unroll
    for (int c = 0; c < GCH; ++c) rs += prs[(g * GCH + c) * 64 + f];
    const int s = gstart[g];
    const int e = (g == G_GRAPHS - 1) ? N_NODES : gstart[g + 1];
    float cnt = (float)(e - s);
    __shared__ float emb[64];
    emb[f] = gWp[0] * cnt + gWp[1] * gMn[g * 64 + f] + gWp[2] * gMx[g * 64 + f] +
             gWp[3] * rs + gWp[4] * gSm[g * 64 + f] + gbp[0];
    __syncthreads();
    if (f < OUTD) {
        float a = bout[f];
        const float* wr = Wout + f * 64;
#pragma unroll
        for (int k = 0; k < 64; ++k) a = fmaf(emb[k], wr[k], a);
        out[g * OUTD + f] = a;
    }
}

// ---------------- launch ----------------

extern "C" void kernel_launch(void* const* d_in, const int* in_sizes, int n_in,
                              void* d_out, int out_size, void* d_ws, size_t ws_size,
                              hipStream_t stream) {
    const float* x     = (const float*)d_in[0];
    const int*   ei    = (const int*)d_in[1];
    const int*   batch = (const int*)d_in[2];
    const float* Wlin  = (const float*)d_in[3];
    const float* blin  = (const float*)d_in[4];
    const float* t     = (const float*)d_in[5];
    const float* Wproj = (const float*)d_in[6];
    const float* bproj = (const float*)d_in[7];
    const float* Wc    = (const float*)d_in[8];
    const float* bc    = (const float*)d_in[9];
    const float* gWlin = (const float*)d_in[10];
    const float* gblin = (const float*)d_in[11];
    const float* gt    = (const float*)d_in[12];
    const float* gWproj= (const float*)d_in[13];
    const float* gbproj= (const float*)d_in[14];
    const float* Wout  = (const float*)d_in[15];
    const float* bout  = (const float*)d_in[16];
    float* out = (float*)d_out;

    const int* src = ei;
    const int* dst = ei + E_EDGES;

    // workspace layout
    char* p = (char*)d_ws;
    float* bufMsg = (float*)p; p += (size_t)N_NODES * FDIM * sizeof(float);
    float* bufH   = (float*)p; p += (size_t)N_NODES * FDIM * sizeof(float);
    int* offsets  = (int*)p;   p += (size_t)(N_NODES + 1) * sizeof(int);
    int* gstart   = (int*)p;   p += (size_t)G_GRAPHS * sizeof(int);
    int* bucketCount  = (int*)p; p += (size_t)KBUK * 16 * sizeof(int);
    int* bucketStart  = (int*)p; p += (size_t)(KBUK + 1) * sizeof(int);
    int* bucketCursor = (int*)p; p += (size_t)KBUK * 16 * sizeof(int);
    int* srcSorted= (int*)p;   p += (size_t)E_EDGES * sizeof(int);
    float* pmn = (float*)p;    p += (size_t)G_GRAPHS * GCH * 64 * sizeof(float);
    float* pmx = (float*)p;    p += (size_t)G_GRAPHS * GCH * 64 * sizeof(float);
    float* psm = (float*)p;    p += (size_t)G_GRAPHS * GCH * 64 * sizeof(float);
    float* prs = (float*)p;    p += (size_t)G_GRAPHS * GCH * 64 * sizeof(float);
    float* gMn = (float*)p;    p += (size_t)G_GRAPHS * 64 * sizeof(float);
    float* gMx = (float*)p;    p += (size_t)G_GRAPHS * 64 * sizeof(float);
    float* gSm = (float*)p;    p += (size_t)G_GRAPHS * 64 * sizeof(float);
    float* gBias = (float*)p;  p += (size_t)G_GRAPHS * 64 * sizeof(float);
    int* ebuf = (int*)bufMsg;  // dead until lin layer 0 runs (after bsort)

    hipMemsetAsync(bucketCount, 0, (size_t)KBUK * 16 * sizeof(int), stream);

    const int NB = (N_NODES + 255) / 256;
    bhist_kernel<<<SEBLK, 256, 0, stream>>>(dst, bucketCount);
    bscan_kernel<<<1, 256, 0, stream>>>(bucketCount, bucketStart, bucketCursor, offsets);
    bscatter_kernel<<<SEBLK, 256, 0, stream>>>(src, dst, bucketCursor, ebuf);
    bsort_kernel<<<KBUK, 256, 0, stream>>>(ebuf, bucketStart, offsets, srcSorted);
    bound_kernel<<<NB, 256, 0, stream>>>(batch, gstart);

    const int LB = (N_NODES + 63) / 64;
    const int AB = (N_NODES + 3) / 4;
    const size_t LDS_DUAL = 3 * 1024 * sizeof(float4);    // 48 KB
    const size_t LDS_SINGLE = 2 * 1024 * sizeof(float4);  // 32 KB

    // layer 0: h = x
    lin_kernel<true><<<LB, 256, LDS_DUAL, stream>>>(x, Wlin, blin, Wc, bc, bufMsg, bufH);
    agg_kernel<<<AB, 256, 0, stream>>>(bufMsg, offsets, srcSorted, t, Wproj, bproj, bufH);
    // layer 1: h = bufH (combine written in place)
    lin_kernel<true><<<LB, 256, LDS_DUAL, stream>>>(bufH, Wlin + 4096, blin + 64,
                                                    Wc + 4096, bc + 64, bufMsg, bufH);
    agg_kernel<<<AB, 256, 0, stream>>>(bufMsg, offsets, srcSorted, t + 64, Wproj + 5,
                                       bproj + 1, bufH);
    // global conv message
    lin_kernel<false><<<LB, 256, LDS_SINGLE, stream>>>(bufH, gWlin, gblin, nullptr,
                                                       nullptr, bufMsg, nullptr);
    gaggA_kernel<<<G_GRAPHS * GCH, 256, 0, stream>>>(bufMsg, gstart, pmn, pmx, psm);
    gaggB_kernel<<<G_GRAPHS, 64, 0, stream>>>(pmn, pmx, psm, gt, gMn, gMx, gSm, gBias);
    gaggC_kernel<<<G_GRAPHS * GCH, 256, 0, stream>>>(bufMsg, gstart, gBias, prs);
    gaggD_kernel<<<G_GRAPHS, 64, 0, stream>>>(prs, gstart, gMn, gMx, gSm, gWproj,
                                              gbproj, Wout, bout, out);
}

// Round 12
// 327.589 us; speedup vs baseline: 5.2606x; 5.2606x over previous
//
#include <hip/hip_runtime.h>
#include <hip/hip_bf16.h>

#define N_NODES 100000
#define E_EDGES 1600000
#define FDIM 64
#define G_GRAPHS 128
#define OUTD 32
#define CAP 16        // edges cached in LDS per node in agg (== one full iteration)
#define NPB 512       // nodes per bucket (power of 2)
#define NPB_SH 9
#define KBUK ((N_NODES + NPB - 1) / NPB)   // 196 (<= 256)
#define SEB 4096      // edges per block in bucket hist/scatter
#define SEBLK ((E_EDGES + SEB - 1) / SEB)  // 391
#define GCH 16        // chunks per graph in global pooling

__device__ __forceinline__ float4 f4min(float4 a, float4 b) {
    return make_float4(fminf(a.x,b.x), fminf(a.y,b.y), fminf(a.z,b.z), fminf(a.w,b.w));
}
__device__ __forceinline__ float4 f4max(float4 a, float4 b) {
    return make_float4(fmaxf(a.x,b.x), fmaxf(a.y,b.y), fmaxf(a.z,b.z), fmaxf(a.w,b.w));
}
__device__ __forceinline__ float4 f4add(float4 a, float4 b) {
    return make_float4(a.x+b.x, a.y+b.y, a.z+b.z, a.w+b.w);
}

// ---------------- CSR build (bucketed) ----------------

__global__ __launch_bounds__(256) void bhist_kernel(const int* __restrict__ dst,
                                                    int* __restrict__ bucketCount) {
    __shared__ int h[KBUK];
    for (int i = threadIdx.x; i < KBUK; i += 256) h[i] = 0;
    __syncthreads();
    const int base = blockIdx.x * SEB;
#pragma unroll
    for (int i = 0; i < 16; ++i) {
        int e = base + i * 256 + threadIdx.x;
        if (e < E_EDGES) atomicAdd(&h[dst[e] >> NPB_SH], 1);
    }
    __syncthreads();
    for (int i = threadIdx.x; i < KBUK; i += 256)
        if (h[i]) atomicAdd(&bucketCount[i * 16], h[i]);  // line-padded
}

__global__ __launch_bounds__(256) void bscan_kernel(const int* __restrict__ bucketCount,
                                                    int* __restrict__ bucketStart,
                                                    int* __restrict__ bucketCursor,
                                                    int* __restrict__ offsets) {
    __shared__ int s[256];
    const int tid = threadIdx.x;
    int v = (tid < KBUK) ? bucketCount[tid * 16] : 0;
    s[tid] = v;
    __syncthreads();
    for (int off = 1; off < 256; off <<= 1) {
        int t = 0;
        if (tid >= off) t = s[tid - off];
        __syncthreads();
        if (tid >= off) s[tid] += t;
        __syncthreads();
    }
    int excl = s[tid] - v;
    if (tid < KBUK) { bucketStart[tid] = excl; bucketCursor[tid * 16] = excl; }
    if (tid == 0) { bucketStart[KBUK] = E_EDGES; offsets[N_NODES] = E_EDGES; }
}

__global__ __launch_bounds__(256) void bscatter_kernel(const int* __restrict__ src,
                                                       const int* __restrict__ dst,
                                                       int* __restrict__ bucketCursor,
                                                       int* __restrict__ ebuf) {
    __shared__ int h[KBUK], resbase[KBUK], lcur[KBUK];
    for (int i = threadIdx.x; i < KBUK; i += 256) { h[i] = 0; lcur[i] = 0; }
    __syncthreads();
    const int base = blockIdx.x * SEB;
#pragma unroll
    for (int i = 0; i < 16; ++i) {
        int e = base + i * 256 + threadIdx.x;
        if (e < E_EDGES) atomicAdd(&h[dst[e] >> NPB_SH], 1);
    }
    __syncthreads();
    for (int i = threadIdx.x; i < KBUK; i += 256)
        resbase[i] = h[i] ? atomicAdd(&bucketCursor[i * 16], h[i]) : 0;
    __syncthreads();
#pragma unroll
    for (int i = 0; i < 16; ++i) {
        int e = base + i * 256 + threadIdx.x;
        if (e < E_EDGES) {
            int d = dst[e];
            int b = d >> NPB_SH;
            int pos = resbase[b] + atomicAdd(&lcur[b], 1);
            ebuf[pos] = (src[e] << NPB_SH) | (d & (NPB - 1));
        }
    }
}

__global__ __launch_bounds__(256) void bsort_kernel(const int* __restrict__ ebuf,
                                                    const int* __restrict__ bucketStart,
                                                    int* __restrict__ offsets,
                                                    int* __restrict__ srcSorted) {
    __shared__ int cnt[NPB];
    __shared__ int cur[NPB];
    __shared__ int wsum[4];
    const int b = blockIdx.x;
    const int tid = threadIdx.x;
    const int ebase = bucketStart[b], eend = bucketStart[b + 1];
    const int nbase = b * NPB;
    cnt[tid] = 0; cnt[tid + 256] = 0;
    __syncthreads();
    for (int e = ebase + tid; e < eend; e += 256)
        atomicAdd(&cnt[ebuf[e] & (NPB - 1)], 1);
    __syncthreads();
    int v0 = cnt[2 * tid], v1 = cnt[2 * tid + 1];
    int s = v0 + v1;
    const int lane = tid & 63, wv = tid >> 6;
    int incl = s;
#pragma unroll
    for (int off = 1; off < 64; off <<= 1) {
        int o = __shfl_up(incl, off);
        if (lane >= off) incl += o;
    }
    if (lane == 63) wsum[wv] = incl;
    __syncthreads();
    int wpre = 0;
#pragma unroll
    for (int w = 0; w < 4; ++w) wpre += (w < wv) ? wsum[w] : 0;
    int excl = wpre + incl - s;
    cur[2 * tid] = excl; cur[2 * tid + 1] = excl + v0;
    int n0 = nbase + 2 * tid;
    if (n0 < N_NODES) offsets[n0] = ebase + excl;
    if (n0 + 1 < N_NODES) offsets[n0 + 1] = ebase + excl + v0;
    __syncthreads();
    for (int e = ebase + tid; e < eend; e += 256) {
        int u = ebuf[e];
        int pos = ebase + atomicAdd(&cur[u & (NPB - 1)], 1);
        srcSorted[pos] = u >> NPB_SH;
    }
}

// batch is sorted -> graph g starts where batch changes value. No atomics.
__global__ __launch_bounds__(256) void bound_kernel(const int* __restrict__ batch,
                                                    int* __restrict__ gstart) {
    int i = blockIdx.x * 256 + threadIdx.x;
    if (i >= N_NODES) return;
    if (i == 0) {
        gstart[batch[0]] = 0;
    } else {
        int b = batch[i], pb = batch[i - 1];
        if (b != pb) gstart[b] = i;
    }
}

// ---------------- linear: out = in@W.T + b  (4x4 register-tiled) ----------------
// 256 threads = 16 node-quads (ni) x 16 feature-quads (fj); each thread computes
// a 4-node x 4-feature tile. LDS: h + W tiles, float4 col-swizzled with
// col ^ ((row>>2)&7): h reads broadcast (4 unique), W reads 2-way (free),
// stores linear. #pragma unroll 2 caps load hoisting (round-10 spill lesson:
// full unroll -> 256 VGPR -> 1.9GB scratch traffic).
// In-place safe (out == in): block stages its own 64 rows before the barrier.

__global__ __launch_bounds__(256) void lin_kernel(const float* __restrict__ in,
                                                  const float* __restrict__ W,
                                                  const float* __restrict__ b,
                                                  float* __restrict__ outBuf) {
    __shared__ __align__(16) float4 shH[1024];  // 16 KB
    __shared__ __align__(16) float4 shW[1024];  // 16 KB
    const int tid = threadIdx.x;
    const int base = blockIdx.x * 64;
#pragma unroll
    for (int i = 0; i < 4; ++i) {
        int j = tid + i * 256;                 // float4 index in 64x64 tile
        int row = j >> 4, col = j & 15;
        int swz = row * 16 + (col ^ ((row >> 2) & 7));
        if (base + row < N_NODES)
            shH[swz] = ((const float4*)in)[(size_t)base * 16 + j];
        shW[swz] = ((const float4*)W)[j];
    }
    __syncthreads();
    const int fj = tid & 15, ni = tid >> 4;
    float acc[4][4] = {{0}};
    const int hs = ni & 7;   // (row>>2)&7 for rows 4ni+r (r<4)
    const int ws = fj & 7;   // (row>>2)&7 for rows 4fj+j (j<4)
#pragma unroll 2
    for (int kk = 0; kk < 16; ++kk) {
        const int hk = kk ^ hs, wk = kk ^ ws;
        float4 h0 = shH[(4 * ni + 0) * 16 + hk];
        float4 h1 = shH[(4 * ni + 1) * 16 + hk];
        float4 h2 = shH[(4 * ni + 2) * 16 + hk];
        float4 h3 = shH[(4 * ni + 3) * 16 + hk];
#pragma unroll
        for (int j = 0; j < 4; ++j) {
            float4 wv = shW[(4 * fj + j) * 16 + wk];
            acc[0][j] += h0.x * wv.x + h0.y * wv.y + h0.z * wv.z + h0.w * wv.w;
            acc[1][j] += h1.x * wv.x + h1.y * wv.y + h1.z * wv.z + h1.w * wv.w;
            acc[2][j] += h2.x * wv.x + h2.y * wv.y + h2.z * wv.z + h2.w * wv.w;
            acc[3][j] += h3.x * wv.x + h3.y * wv.y + h3.z * wv.z + h3.w * wv.w;
        }
    }
    float4 b4 = *(const float4*)(b + 4 * fj);
#pragma unroll
    for (int r = 0; r < 4; ++r) {
        int node = base + 4 * ni + r;
        if (node < N_NODES) {
            float4 o = make_float4(acc[r][0] + b4.x, acc[r][1] + b4.y,
                                   acc[r][2] + b4.z, acc[r][3] + b4.w);
            *(float4*)(outBuf + (size_t)node * 64 + 4 * fj) = o;
        }
    }
}

// ---------------- per-node adaptive-relu aggregation ----------------
// wave per node; lane = (edge group g = lane>>4, feature quad fq = lane&15).
// deg>=16: iter0 branchless (all slots cached), then branchless full-16 iters,
// then one masked tail.

__global__ __launch_bounds__(256) void agg_kernel(const float* __restrict__ msg,
                                                  const int* __restrict__ offsets,
                                                  const int* __restrict__ srcSorted,
                                                  const float* __restrict__ tptr,
                                                  const float* __restrict__ Wp,
                                                  const float* __restrict__ bp,
                                                  float* __restrict__ hbuf) {
    __shared__ float4 cache[4][CAP][16];  // 16 KB
    const int w = threadIdx.x >> 6;
    const int lane = threadIdx.x & 63;
    const int g = lane >> 4;
    const int fq = lane & 15;
    const int node = blockIdx.x * 4 + w;
    if (node >= N_NODES) return;
    const int start = offsets[node], end = offsets[node + 1];
    const int deg = end - start;
    const float4* mq = (const float4*)msg + fq;  // row stride = 16 float4
    const float INF = __builtin_inff();
    float4 mn = make_float4(INF, INF, INF, INF);
    float4 mx = make_float4(-INF, -INF, -INF, -INF);
    float4 sm = make_float4(0.f, 0.f, 0.f, 0.f);

#define ACC1(v) { mn = f4min(mn, v); mx = f4max(mx, v); sm = f4add(sm, v); }

    if (deg >= 16) {
        {
            int i0 = start + g;
            int s0 = srcSorted[i0], s1 = srcSorted[i0 + 4];
            int s2 = srcSorted[i0 + 8], s3 = srcSorted[i0 + 12];
            float4 v0 = mq[(size_t)s0 * 16], v1 = mq[(size_t)s1 * 16];
            float4 v2 = mq[(size_t)s2 * 16], v3 = mq[(size_t)s3 * 16];
            cache[w][g][fq] = v0; cache[w][g + 4][fq] = v1;
            cache[w][g + 8][fq] = v2; cache[w][g + 12][fq] = v3;
            ACC1(v0) ACC1(v1) ACC1(v2) ACC1(v3)
        }
        int e = start + 16;
        for (; e + 16 <= end; e += 16) {
            int i0 = e + g;
            int s0 = srcSorted[i0], s1 = srcSorted[i0 + 4];
            int s2 = srcSorted[i0 + 8], s3 = srcSorted[i0 + 12];
            float4 v0 = mq[(size_t)s0 * 16], v1 = mq[(size_t)s1 * 16];
            float4 v2 = mq[(size_t)s2 * 16], v3 = mq[(size_t)s3 * 16];
            ACC1(v0) ACC1(v1) ACC1(v2) ACC1(v3)
        }
        if (e < end) {
            int i0 = e + g, i1 = i0 + 4, i2 = i0 + 8, i3 = i0 + 12;
            bool ok0 = i0 < end, ok1 = i1 < end, ok2 = i2 < end, ok3 = i3 < end;
            int s0 = 0, s1 = 0, s2 = 0, s3 = 0;
            if (ok0) s0 = srcSorted[i0];
            if (ok1) s1 = srcSorted[i1];
            if (ok2) s2 = srcSorted[i2];
            if (ok3) s3 = srcSorted[i3];
            float4 v0, v1, v2, v3;
            if (ok0) v0 = mq[(size_t)s0 * 16];
            if (ok1) v1 = mq[(size_t)s1 * 16];
            if (ok2) v2 = mq[(size_t)s2 * 16];
            if (ok3) v3 = mq[(size_t)s3 * 16];
            if (ok0) ACC1(v0)
            if (ok1) ACC1(v1)
            if (ok2) ACC1(v2)
            if (ok3) ACC1(v3)
        }
    } else {
        int i0 = start + g, i1 = i0 + 4, i2 = i0 + 8, i3 = i0 + 12;
        bool ok0 = i0 < end, ok1 = i1 < end, ok2 = i2 < end, ok3 = i3 < end;
        int s0 = 0, s1 = 0, s2 = 0, s3 = 0;
        if (ok0) s0 = srcSorted[i0];
        if (ok1) s1 = srcSorted[i1];
        if (ok2) s2 = srcSorted[i2];
        if (ok3) s3 = srcSorted[i3];
        float4 v0, v1, v2, v3;
        if (ok0) v0 = mq[(size_t)s0 * 16];
        if (ok1) v1 = mq[(size_t)s1 * 16];
        if (ok2) v2 = mq[(size_t)s2 * 16];
        if (ok3) v3 = mq[(size_t)s3 * 16];
        if (ok0) { cache[w][g][fq] = v0;      ACC1(v0) }
        if (ok1) { cache[w][g + 4][fq] = v1;  ACC1(v1) }
        if (ok2) { cache[w][g + 8][fq] = v2;  ACC1(v2) }
        if (ok3) { cache[w][g + 12][fq] = v3; ACC1(v3) }
    }
#pragma unroll
    for (int off = 16; off <= 32; off <<= 1) {
        mn.x = fminf(mn.x, __shfl_xor(mn.x, off)); mn.y = fminf(mn.y, __shfl_xor(mn.y, off));
        mn.z = fminf(mn.z, __shfl_xor(mn.z, off)); mn.w = fminf(mn.w, __shfl_xor(mn.w, off));
        mx.x = fmaxf(mx.x, __shfl_xor(mx.x, off)); mx.y = fmaxf(mx.y, __shfl_xor(mx.y, off));
        mx.z = fmaxf(mx.z, __shfl_xor(mx.z, off)); mx.w = fmaxf(mx.w, __shfl_xor(mx.w, off));
        sm.x += __shfl_xor(sm.x, off); sm.y += __shfl_xor(sm.y, off);
        sm.z += __shfl_xor(sm.z, off); sm.w += __shfl_xor(sm.w, off);
    }
    float4 tv = *(const float4*)(tptr + 4 * fq);
    tv.x = fminf(fmaxf(tv.x, 0.f), 1.f); tv.y = fminf(fmaxf(tv.y, 0.f), 1.f);
    tv.z = fminf(fmaxf(tv.z, 0.f), 1.f); tv.w = fminf(fmaxf(tv.w, 0.f), 1.f);
    float4 bias;
    bias.x = tv.x * mx.x + (1.f - tv.x) * mn.x;
    bias.y = tv.y * mx.y + (1.f - tv.y) * mn.y;
    bias.z = tv.z * mx.z + (1.f - tv.z) * mn.z;
    bias.w = tv.w * mx.w + (1.f - tv.w) * mn.w;
    float4 rs = make_float4(0.f, 0.f, 0.f, 0.f);

#define RACC(v) { rs.x += fmaxf(v.x - bias.x, 0.f); rs.y += fmaxf(v.y - bias.y, 0.f); \
                  rs.z += fmaxf(v.z - bias.z, 0.f); rs.w += fmaxf(v.w - bias.w, 0.f); }

    if (deg >= 16) {
#pragma unroll
        for (int i = 0; i < 4; ++i) {
            float4 v = cache[w][i * 4 + g][fq];
            RACC(v)
        }
        int e = start + 16;
        for (; e + 16 <= end; e += 16) {
            int i0 = e + g;
            int s0 = srcSorted[i0], s1 = srcSorted[i0 + 4];
            int s2 = srcSorted[i0 + 8], s3 = srcSorted[i0 + 12];
            float4 v0 = mq[(size_t)s0 * 16], v1 = mq[(size_t)s1 * 16];
            float4 v2 = mq[(size_t)s2 * 16], v3 = mq[(size_t)s3 * 16];
            RACC(v0) RACC(v1) RACC(v2) RACC(v3)
        }
        if (e < end) {
            int i0 = e + g, i1 = i0 + 4, i2 = i0 + 8, i3 = i0 + 12;
            bool ok0 = i0 < end, ok1 = i1 < end, ok2 = i2 < end, ok3 = i3 < end;
            int s0 = 0, s1 = 0, s2 = 0, s3 = 0;
            if (ok0) s0 = srcSorted[i0];
            if (ok1) s1 = srcSorted[i1];
            if (ok2) s2 = srcSorted[i2];
            if (ok3) s3 = srcSorted[i3];
            float4 v0, v1, v2, v3;
            if (ok0) v0 = mq[(size_t)s0 * 16];
            if (ok1) v1 = mq[(size_t)s1 * 16];
            if (ok2) v2 = mq[(size_t)s2 * 16];
            if (ok3) v3 = mq[(size_t)s3 * 16];
            if (ok0) RACC(v0)
            if (ok1) RACC(v1)
            if (ok2) RACC(v2)
            if (ok3) RACC(v3)
        }
    } else {
        for (int idx = start + g; idx < end; idx += 4) {
            float4 v = cache[w][idx - start][fq];
            RACC(v)
        }
    }
#pragma unroll
    for (int off = 16; off <= 32; off <<= 1) {
        rs.x += __shfl_xor(rs.x, off); rs.y += __shfl_xor(rs.y, off);
        rs.z += __shfl_xor(rs.z, off); rs.w += __shfl_xor(rs.w, off);
    }
    if (g == 0) {
        float cnt = (float)deg;
        float w0 = Wp[0], w1 = Wp[1], w2 = Wp[2], w3 = Wp[3], w4 = Wp[4], b0 = bp[0];
        float4* hp = (float4*)(hbuf + (size_t)node * 64 + 4 * fq);
        float4 h = *hp;
        h.x += w0 * cnt + w1 * mn.x + w2 * mx.x + w3 * rs.x + w4 * sm.x + b0;
        h.y += w0 * cnt + w1 * mn.y + w2 * mx.y + w3 * rs.y + w4 * sm.y + b0;
        h.z += w0 * cnt + w1 * mn.z + w2 * mx.z + w3 * rs.z + w4 * sm.z + b0;
        h.w += w0 * cnt + w1 * mn.w + w2 * mx.w + w3 * rs.w + w4 * sm.w + b0;
        *hp = h;
    }
#undef ACC1
#undef RACC
}

// ---------------- global pooling (4-phase, parallel) ----------------

__global__ __launch_bounds__(256) void gaggA_kernel(const float* __restrict__ msg,
                                                    const int* __restrict__ gstart,
                                                    float* __restrict__ pmn,
                                                    float* __restrict__ pmx,
                                                    float* __restrict__ psm) {
    const int bid = blockIdx.x;
    const int g = bid >> 4, c = bid & (GCH - 1);
    const int s = gstart[g];
    const int e = (g == G_GRAPHS - 1) ? N_NODES : gstart[g + 1];
    const int clen = (e - s + GCH - 1) / GCH;
    const int cs = s + c * clen;
    const int ce = (cs + clen < e) ? (cs + clen) : e;
    const int f = threadIdx.x & 63, r = threadIdx.x >> 6;
    float mn = __builtin_inff(), mx = -__builtin_inff(), sm = 0.f;
    for (int i = cs + r; i < ce; i += 4) {
        float v = msg[(size_t)i * 64 + f];
        mn = fminf(mn, v); mx = fmaxf(mx, v); sm += v;
    }
    __shared__ float smn[4][64], smx[4][64], ssm[4][64];
    smn[r][f] = mn; smx[r][f] = mx; ssm[r][f] = sm;
    __syncthreads();
    if (r == 0) {
        pmn[bid * 64 + f] = fminf(fminf(smn[0][f], smn[1][f]), fminf(smn[2][f], smn[3][f]));
        pmx[bid * 64 + f] = fmaxf(fmaxf(smx[0][f], smx[1][f]), fmaxf(smx[2][f], smx[3][f]));
        psm[bid * 64 + f] = ssm[0][f] + ssm[1][f] + ssm[2][f] + ssm[3][f];
    }
}

__global__ __launch_bounds__(64) void gaggB_kernel(const float* __restrict__ pmn,
                                                   const float* __restrict__ pmx,
                                                   const float* __restrict__ psm,
                                                   const float* __restrict__ gt,
                                                   float* __restrict__ gMn,
                                                   float* __restrict__ gMx,
                                                   float* __restrict__ gSm,
                                                   float* __restrict__ gBias) {
    const int g = blockIdx.x, f = threadIdx.x;
    float mn = __builtin_inff(), mx = -__builtin_inff(), sm = 0.f;
#pragma unroll
    for (int c = 0; c < GCH; ++c) {
        int i = (g * GCH + c) * 64 + f;
        mn = fminf(mn, pmn[i]); mx = fmaxf(mx, pmx[i]); sm += psm[i];
    }
    float tv = fminf(fmaxf(gt[f], 0.f), 1.f);
    gMn[g * 64 + f] = mn; gMx[g * 64 + f] = mx; gSm[g * 64 + f] = sm;
    gBias[g * 64 + f] = tv * mx + (1.f - tv) * mn;
}

__global__ __launch_bounds__(256) void gaggC_kernel(const float* __restrict__ msg,
                                                    const int* __restrict__ gstart,
                                                    const float* __restrict__ gBias,
                                                    float* __restrict__ prs) {
    const int bid = blockIdx.x;
    const int g = bid >> 4, c = bid & (GCH - 1);
    const int s = gstart[g];
    const int e = (g == G_GRAPHS - 1) ? N_NODES : gstart[g + 1];
    const int clen = (e - s + GCH - 1) / GCH;
    const int cs = s + c * clen;
    const int ce = (cs + clen < e) ? (cs + clen) : e;
    const int f = threadIdx.x & 63, r = threadIdx.x >> 6;
    const float bias = gBias[g * 64 + f];
    float rs = 0.f;
    for (int i = cs + r; i < ce; i += 4) {
        float v = msg[(size_t)i * 64 + f];
        rs += fmaxf(v - bias, 0.f);
    }
    __shared__ float srs[4][64];
    srs[r][f] = rs;
    __syncthreads();
    if (r == 0)
        prs[bid * 64 + f] = srs[0][f] + srs[1][f] + srs[2][f] + srs[3][f];
}

__global__ __launch_bounds__(64) void gaggD_kernel(const float* __restrict__ prs,
                                                   const int* __restrict__ gstart,
                                                   const float* __restrict__ gMn,
                                                   const float* __restrict__ gMx,
                                                   const float* __restrict__ gSm,
                                                   const float* __restrict__ gWp,
                                                   const float* __restrict__ gbp,
                                                   const float* __restrict__ Wout,
                                                   const float* __restrict__ bout,
                                                   float* __restrict__ out) {
    const int g = blockIdx.x, f = threadIdx.x;
    float rs = 0.f;
#pragma unroll
    for (int c = 0; c < GCH; ++c) rs += prs[(g * GCH + c) * 64 + f];
    const int s = gstart[g];
    const int e = (g == G_GRAPHS - 1) ? N_NODES : gstart[g + 1];
    float cnt = (float)(e - s);
    __shared__ float emb[64];
    emb[f] = gWp[0] * cnt + gWp[1] * gMn[g * 64 + f] + gWp[2] * gMx[g * 64 + f] +
             gWp[3] * rs + gWp[4] * gSm[g * 64 + f] + gbp[0];
    __syncthreads();
    if (f < OUTD) {
        float a = bout[f];
        const float* wr = Wout + f * 64;
#pragma unroll
        for (int k = 0; k < 64; ++k) a = fmaf(emb[k], wr[k], a);
        out[g * OUTD + f] = a;
    }
}

// ---------------- launch ----------------

extern "C" void kernel_launch(void* const* d_in, const int* in_sizes, int n_in,
                              void* d_out, int out_size, void* d_ws, size_t ws_size,
                              hipStream_t stream) {
    const float* x     = (const float*)d_in[0];
    const int*   ei    = (const int*)d_in[1];
    const int*   batch = (const int*)d_in[2];
    const float* Wlin  = (const float*)d_in[3];
    const float* blin  = (const float*)d_in[4];
    const float* t     = (const float*)d_in[5];
    const float* Wproj = (const float*)d_in[6];
    const float* bproj = (const float*)d_in[7];
    const float* Wc    = (const float*)d_in[8];
    const float* bc    = (const float*)d_in[9];
    const float* gWlin = (const float*)d_in[10];
    const float* gblin = (const float*)d_in[11];
    const float* gt    = (const float*)d_in[12];
    const float* gWproj= (const float*)d_in[13];
    const float* gbproj= (const float*)d_in[14];
    const float* Wout  = (const float*)d_in[15];
    const float* bout  = (const float*)d_in[16];
    float* out = (float*)d_out;

    const int* src = ei;
    const int* dst = ei + E_EDGES;

    // workspace layout
    char* p = (char*)d_ws;
    float* bufMsg = (float*)p; p += (size_t)N_NODES * FDIM * sizeof(float);
    float* bufH   = (float*)p; p += (size_t)N_NODES * FDIM * sizeof(float);
    int* offsets  = (int*)p;   p += (size_t)(N_NODES + 1) * sizeof(int);
    int* gstart   = (int*)p;   p += (size_t)G_GRAPHS * sizeof(int);
    int* bucketCount  = (int*)p; p += (size_t)KBUK * 16 * sizeof(int);
    int* bucketStart  = (int*)p; p += (size_t)(KBUK + 1) * sizeof(int);
    int* bucketCursor = (int*)p; p += (size_t)KBUK * 16 * sizeof(int);
    int* srcSorted= (int*)p;   p += (size_t)E_EDGES * sizeof(int);
    float* pmn = (float*)p;    p += (size_t)G_GRAPHS * GCH * 64 * sizeof(float);
    float* pmx = (float*)p;    p += (size_t)G_GRAPHS * GCH * 64 * sizeof(float);
    float* psm = (float*)p;    p += (size_t)G_GRAPHS * GCH * 64 * sizeof(float);
    float* prs = (float*)p;    p += (size_t)G_GRAPHS * GCH * 64 * sizeof(float);
    float* gMn = (float*)p;    p += (size_t)G_GRAPHS * 64 * sizeof(float);
    float* gMx = (float*)p;    p += (size_t)G_GRAPHS * 64 * sizeof(float);
    float* gSm = (float*)p;    p += (size_t)G_GRAPHS * 64 * sizeof(float);
    float* gBias = (float*)p;  p += (size_t)G_GRAPHS * 64 * sizeof(float);
    int* ebuf = (int*)bufMsg;  // dead until lin layer 0 runs (after bsort)

    hipMemsetAsync(bucketCount, 0, (size_t)KBUK * 16 * sizeof(int), stream);

    const int NB = (N_NODES + 255) / 256;
    bhist_kernel<<<SEBLK, 256, 0, stream>>>(dst, bucketCount);
    bscan_kernel<<<1, 256, 0, stream>>>(bucketCount, bucketStart, bucketCursor, offsets);
    bscatter_kernel<<<SEBLK, 256, 0, stream>>>(src, dst, bucketCursor, ebuf);
    bsort_kernel<<<KBUK, 256, 0, stream>>>(ebuf, bucketStart, offsets, srcSorted);
    bound_kernel<<<NB, 256, 0, stream>>>(batch, gstart);

    const int LB = (N_NODES + 63) / 64;
    const int AB = (N_NODES + 3) / 4;

    // layer 0: h = x.  msg = x@Wm0.T+b ; hC = x@Wc0.T+bc (separate launches)
    lin_kernel<<<LB, 256, 0, stream>>>(x, Wlin, blin, bufMsg);
    lin_kernel<<<LB, 256, 0, stream>>>(x, Wc, bc, bufH);
    agg_kernel<<<AB, 256, 0, stream>>>(bufMsg, offsets, srcSorted, t, Wproj, bproj, bufH);
    // layer 1: msg = h@Wm1.T+b first (reads bufH), then combine in place
    lin_kernel<<<LB, 256, 0, stream>>>(bufH, Wlin + 4096, blin + 64, bufMsg);
    lin_kernel<<<LB, 256, 0, stream>>>(bufH, Wc + 4096, bc + 64, bufH);
    agg_kernel<<<AB, 256, 0, stream>>>(bufMsg, offsets, srcSorted, t + 64, Wproj + 5,
                                       bproj + 1, bufH);
    // global conv message
    lin_kernel<<<LB, 256, 0, stream>>>(bufH, gWlin, gblin, bufMsg);
    gaggA_kernel<<<G_GRAPHS * GCH, 256, 0, stream>>>(bufMsg, gstart, pmn, pmx, psm);
    gaggB_kernel<<<G_GRAPHS, 64, 0, stream>>>(pmn, pmx, psm, gt, gMn, gMx, gSm, gBias);
    gaggC_kernel<<<G_GRAPHS * GCH, 256, 0, stream>>>(bufMsg, gstart, gBias, prs);
    gaggD_kernel<<<G_GRAPHS, 64, 0, stream>>>(prs, gstart, gMn, gMx, gSm, gWproj,
                                              gbproj, Wout, bout, out);
}

// Round 13
// 306.694 us; speedup vs baseline: 5.6190x; 1.0681x over previous
//
#include <hip/hip_runtime.h>
#include <hip/hip_bf16.h>

#define N_NODES 100000
#define E_EDGES 1600000
#define FDIM 64
#define G_GRAPHS 128
#define OUTD 32
#define CAP 16        // edges cached in LDS per node in agg
#define NPB 512       // nodes per bucket (power of 2)
#define NPB_SH 9
#define KBUK ((N_NODES + NPB - 1) / NPB)   // 196 (<= 256)
#define CAPB 10240    // fixed edge capacity per bucket region (mean 8192, +23 sigma)
#define SEB 4096      // edges per block in bucket scatter
#define SEBLK ((E_EDGES + SEB - 1) / SEB)  // 391
#define GCH 16        // chunks per graph in global pooling

__device__ __forceinline__ float4 f4min(float4 a, float4 b) {
    return make_float4(fminf(a.x,b.x), fminf(a.y,b.y), fminf(a.z,b.z), fminf(a.w,b.w));
}
__device__ __forceinline__ float4 f4max(float4 a, float4 b) {
    return make_float4(fmaxf(a.x,b.x), fmaxf(a.y,b.y), fmaxf(a.z,b.z), fmaxf(a.w,b.w));
}
__device__ __forceinline__ float4 f4add(float4 a, float4 b) {
    return make_float4(a.x+b.x, a.y+b.y, a.z+b.z, a.w+b.w);
}
// bf16x4 (uint2) -> float4 ; values [0..3] = (x.lo, x.hi, y.lo, y.hi)
__device__ __forceinline__ float4 bf2f4(uint2 u) {
    return make_float4(__uint_as_float(u.x << 16),
                       __uint_as_float(u.x & 0xffff0000u),
                       __uint_as_float(u.y << 16),
                       __uint_as_float(u.y & 0xffff0000u));
}
// f32 -> bf16 (round to nearest even)
__device__ __forceinline__ unsigned short f2bf(float f) {
    unsigned int u = __float_as_uint(f);
    return (unsigned short)((u + 0x7fffu + ((u >> 16) & 1u)) >> 16);
}

// ---------------- CSR build (bucketed, fixed-capacity regions) ----------------

__global__ __launch_bounds__(256) void binit_kernel(int* __restrict__ bucketCursor) {
    int i = threadIdx.x;
    if (i < KBUK) bucketCursor[i * 16] = i * CAPB;  // line-padded counters
}

// coarse scatter into fixed bucket regions; per-block LDS hist -> one global
// atomic reservation per (bucket, block). Packed (src<<9)|dstLow.
__global__ __launch_bounds__(256) void bscatter_kernel(const int* __restrict__ src,
                                                       const int* __restrict__ dst,
                                                       int* __restrict__ bucketCursor,
                                                       int* __restrict__ ebuf) {
    __shared__ int h[KBUK], resbase[KBUK], lcur[KBUK];
    for (int i = threadIdx.x; i < KBUK; i += 256) { h[i] = 0; lcur[i] = 0; }
    __syncthreads();
    const int base = blockIdx.x * SEB;
#pragma unroll
    for (int i = 0; i < 16; ++i) {
        int e = base + i * 256 + threadIdx.x;
        if (e < E_EDGES) atomicAdd(&h[dst[e] >> NPB_SH], 1);
    }
    __syncthreads();
    for (int i = threadIdx.x; i < KBUK; i += 256)
        resbase[i] = h[i] ? atomicAdd(&bucketCursor[i * 16], h[i]) : 0;
    __syncthreads();
#pragma unroll
    for (int i = 0; i < 16; ++i) {
        int e = base + i * 256 + threadIdx.x;
        if (e < E_EDGES) {
            int d = dst[e];
            int b = d >> NPB_SH;
            int pos = resbase[b] + atomicAdd(&lcur[b], 1);
            ebuf[pos] = (src[e] << NPB_SH) | (d & (NPB - 1));
        }
    }
}

// scan per-bucket counts (cursor - fixed base) -> compact bucketStart
__global__ __launch_bounds__(256) void bscan_kernel(const int* __restrict__ bucketCursor,
                                                    int* __restrict__ bucketStart,
                                                    int* __restrict__ offsets) {
    __shared__ int s[256];
    const int tid = threadIdx.x;
    int v = (tid < KBUK) ? (bucketCursor[tid * 16] - tid * CAPB) : 0;
    s[tid] = v;
    __syncthreads();
    for (int off = 1; off < 256; off <<= 1) {
        int t = 0;
        if (tid >= off) t = s[tid - off];
        __syncthreads();
        if (tid >= off) s[tid] += t;
        __syncthreads();
    }
    int excl = s[tid] - v;
    if (tid < KBUK) bucketStart[tid] = excl;
    if (tid == 0) { bucketStart[KBUK] = E_EDGES; offsets[N_NODES] = E_EDGES; }
}

// per-bucket counting sort -> offsets[] + srcSorted[]
__global__ __launch_bounds__(256) void bsort_kernel(const int* __restrict__ ebuf,
                                                    const int* __restrict__ bucketStart,
                                                    int* __restrict__ offsets,
                                                    int* __restrict__ srcSorted) {
    __shared__ int cnt[NPB];
    __shared__ int cur[NPB];
    __shared__ int wsum[4];
    const int b = blockIdx.x;
    const int tid = threadIdx.x;
    const int rbase = b * CAPB;                 // read region (fixed)
    const int ebase = bucketStart[b];           // write region (compact)
    const int cb = bucketStart[b + 1] - ebase;  // bucket edge count
    const int nbase = b * NPB;
    cnt[tid] = 0; cnt[tid + 256] = 0;
    __syncthreads();
    for (int e = tid; e < cb; e += 256)
        atomicAdd(&cnt[ebuf[rbase + e] & (NPB - 1)], 1);
    __syncthreads();
    int v0 = cnt[2 * tid], v1 = cnt[2 * tid + 1];
    int s = v0 + v1;
    const int lane = tid & 63, wv = tid >> 6;
    int incl = s;
#pragma unroll
    for (int off = 1; off < 64; off <<= 1) {
        int o = __shfl_up(incl, off);
        if (lane >= off) incl += o;
    }
    if (lane == 63) wsum[wv] = incl;
    __syncthreads();
    int wpre = 0;
#pragma unroll
    for (int w = 0; w < 4; ++w) wpre += (w < wv) ? wsum[w] : 0;
    int excl = wpre + incl - s;
    cur[2 * tid] = excl; cur[2 * tid + 1] = excl + v0;
    int n0 = nbase + 2 * tid;
    if (n0 < N_NODES) offsets[n0] = ebase + excl;
    if (n0 + 1 < N_NODES) offsets[n0 + 1] = ebase + excl + v0;
    __syncthreads();
    for (int e = tid; e < cb; e += 256) {
        int u = ebuf[rbase + e];
        int pos = ebase + atomicAdd(&cur[u & (NPB - 1)], 1);
        srcSorted[pos] = u >> NPB_SH;
    }
}

// batch is sorted -> graph g starts where batch changes value.
__global__ __launch_bounds__(256) void bound_kernel(const int* __restrict__ batch,
                                                    int* __restrict__ gstart) {
    int i = blockIdx.x * 256 + threadIdx.x;
    if (i >= N_NODES) return;
    if (i == 0) {
        gstart[batch[0]] = 0;
    } else {
        int b = batch[i], pb = batch[i - 1];
        if (b != pb) gstart[b] = i;
    }
}

// ---------------- linear: out = in@W.T + b  (4x4 register-tiled) ----------------
// BF16OUT=true stores bf16 (for agg's gather table), else f32.
// #pragma unroll 2 caps load hoisting (round-10 spill lesson).
// In-place safe (outF == in): block stages its own 64 rows before the barrier.

template <bool BF16OUT>
__global__ __launch_bounds__(256) void lin_kernel(const float* __restrict__ in,
                                                  const float* __restrict__ W,
                                                  const float* __restrict__ b,
                                                  float* __restrict__ outF,
                                                  unsigned short* __restrict__ outB) {
    __shared__ __align__(16) float4 shH[1024];  // 16 KB
    __shared__ __align__(16) float4 shW[1024];  // 16 KB
    const int tid = threadIdx.x;
    const int base = blockIdx.x * 64;
#pragma unroll
    for (int i = 0; i < 4; ++i) {
        int j = tid + i * 256;                 // float4 index in 64x64 tile
        int row = j >> 4, col = j & 15;
        int swz = row * 16 + (col ^ ((row >> 2) & 7));
        if (base + row < N_NODES)
            shH[swz] = ((const float4*)in)[(size_t)base * 16 + j];
        shW[swz] = ((const float4*)W)[j];
    }
    __syncthreads();
    const int fj = tid & 15, ni = tid >> 4;
    float acc[4][4] = {{0}};
    const int hs = ni & 7;
    const int ws = fj & 7;
#pragma unroll 2
    for (int kk = 0; kk < 16; ++kk) {
        const int hk = kk ^ hs, wk = kk ^ ws;
        float4 h0 = shH[(4 * ni + 0) * 16 + hk];
        float4 h1 = shH[(4 * ni + 1) * 16 + hk];
        float4 h2 = shH[(4 * ni + 2) * 16 + hk];
        float4 h3 = shH[(4 * ni + 3) * 16 + hk];
#pragma unroll
        for (int j = 0; j < 4; ++j) {
            float4 wv = shW[(4 * fj + j) * 16 + wk];
            acc[0][j] += h0.x * wv.x + h0.y * wv.y + h0.z * wv.z + h0.w * wv.w;
            acc[1][j] += h1.x * wv.x + h1.y * wv.y + h1.z * wv.z + h1.w * wv.w;
            acc[2][j] += h2.x * wv.x + h2.y * wv.y + h2.z * wv.z + h2.w * wv.w;
            acc[3][j] += h3.x * wv.x + h3.y * wv.y + h3.z * wv.z + h3.w * wv.w;
        }
    }
    float4 b4 = *(const float4*)(b + 4 * fj);
#pragma unroll
    for (int r = 0; r < 4; ++r) {
        int node = base + 4 * ni + r;
        if (node < N_NODES) {
            if (BF16OUT) {
                ushort4 o;
                o.x = f2bf(acc[r][0] + b4.x); o.y = f2bf(acc[r][1] + b4.y);
                o.z = f2bf(acc[r][2] + b4.z); o.w = f2bf(acc[r][3] + b4.w);
                *(ushort4*)(outB + (size_t)node * 64 + 4 * fj) = o;
            } else {
                float4 o = make_float4(acc[r][0] + b4.x, acc[r][1] + b4.y,
                                       acc[r][2] + b4.z, acc[r][3] + b4.w);
                *(float4*)(outF + (size_t)node * 64 + 4 * fj) = o;
            }
        }
    }
}

// ---------------- per-node adaptive-relu aggregation (bf16 gather) ----------------
// wave per node; lane = (edge group g = lane>>4, feature quad fq = lane&15).
// Row = 64 bf16 = 128 B; lane loads uint2 (4 bf16). deg>=16: iter0 branchless
// (all slots cached raw), branchless full-16 iters, one masked tail.

__global__ __launch_bounds__(256) void agg_kernel(const unsigned short* __restrict__ msgB,
                                                  const int* __restrict__ offsets,
                                                  const int* __restrict__ srcSorted,
                                                  const float* __restrict__ tptr,
                                                  const float* __restrict__ Wp,
                                                  const float* __restrict__ bp,
                                                  float* __restrict__ hbuf) {
    __shared__ uint2 cache[4][CAP][16];  // 8 KB
    const int w = threadIdx.x >> 6;
    const int lane = threadIdx.x & 63;
    const int g = lane >> 4;
    const int fq = lane & 15;
    const int node = blockIdx.x * 4 + w;
    if (node >= N_NODES) return;
    const int start = offsets[node], end = offsets[node + 1];
    const int deg = end - start;
    const uint2* mq = (const uint2*)msgB + fq;  // row stride = 16 uint2 (128 B)
    const float INF = __builtin_inff();
    float4 mn = make_float4(INF, INF, INF, INF);
    float4 mx = make_float4(-INF, -INF, -INF, -INF);
    float4 sm = make_float4(0.f, 0.f, 0.f, 0.f);

#define ACC1(v) { mn = f4min(mn, v); mx = f4max(mx, v); sm = f4add(sm, v); }

    if (deg >= 16) {
        {
            int i0 = start + g;
            int s0 = srcSorted[i0], s1 = srcSorted[i0 + 4];
            int s2 = srcSorted[i0 + 8], s3 = srcSorted[i0 + 12];
            uint2 u0 = mq[(size_t)s0 * 16], u1 = mq[(size_t)s1 * 16];
            uint2 u2 = mq[(size_t)s2 * 16], u3 = mq[(size_t)s3 * 16];
            cache[w][g][fq] = u0; cache[w][g + 4][fq] = u1;
            cache[w][g + 8][fq] = u2; cache[w][g + 12][fq] = u3;
            float4 v0 = bf2f4(u0), v1 = bf2f4(u1), v2 = bf2f4(u2), v3 = bf2f4(u3);
            ACC1(v0) ACC1(v1) ACC1(v2) ACC1(v3)
        }
        int e = start + 16;
        for (; e + 16 <= end; e += 16) {
            int i0 = e + g;
            int s0 = srcSorted[i0], s1 = srcSorted[i0 + 4];
            int s2 = srcSorted[i0 + 8], s3 = srcSorted[i0 + 12];
            float4 v0 = bf2f4(mq[(size_t)s0 * 16]);
            float4 v1 = bf2f4(mq[(size_t)s1 * 16]);
            float4 v2 = bf2f4(mq[(size_t)s2 * 16]);
            float4 v3 = bf2f4(mq[(size_t)s3 * 16]);
            ACC1(v0) ACC1(v1) ACC1(v2) ACC1(v3)
        }
        if (e < end) {
            int i0 = e + g, i1 = i0 + 4, i2 = i0 + 8, i3 = i0 + 12;
            bool ok0 = i0 < end, ok1 = i1 < end, ok2 = i2 < end, ok3 = i3 < end;
            int s0 = 0, s1 = 0, s2 = 0, s3 = 0;
            if (ok0) s0 = srcSorted[i0];
            if (ok1) s1 = srcSorted[i1];
            if (ok2) s2 = srcSorted[i2];
            if (ok3) s3 = srcSorted[i3];
            float4 v0, v1, v2, v3;
            if (ok0) v0 = bf2f4(mq[(size_t)s0 * 16]);
            if (ok1) v1 = bf2f4(mq[(size_t)s1 * 16]);
            if (ok2) v2 = bf2f4(mq[(size_t)s2 * 16]);
            if (ok3) v3 = bf2f4(mq[(size_t)s3 * 16]);
            if (ok0) ACC1(v0)
            if (ok1) ACC1(v1)
            if (ok2) ACC1(v2)
            if (ok3) ACC1(v3)
        }
    } else {
        int i0 = start + g, i1 = i0 + 4, i2 = i0 + 8, i3 = i0 + 12;
        bool ok0 = i0 < end, ok1 = i1 < end, ok2 = i2 < end, ok3 = i3 < end;
        int s0 = 0, s1 = 0, s2 = 0, s3 = 0;
        if (ok0) s0 = srcSorted[i0];
        if (ok1) s1 = srcSorted[i1];
        if (ok2) s2 = srcSorted[i2];
        if (ok3) s3 = srcSorted[i3];
        uint2 u0, u1, u2, u3;
        if (ok0) u0 = mq[(size_t)s0 * 16];
        if (ok1) u1 = mq[(size_t)s1 * 16];
        if (ok2) u2 = mq[(size_t)s2 * 16];
        if (ok3) u3 = mq[(size_t)s3 * 16];
        if (ok0) { cache[w][g][fq] = u0;      float4 v = bf2f4(u0); ACC1(v) }
        if (ok1) { cache[w][g + 4][fq] = u1;  float4 v = bf2f4(u1); ACC1(v) }
        if (ok2) { cache[w][g + 8][fq] = u2;  float4 v = bf2f4(u2); ACC1(v) }
        if (ok3) { cache[w][g + 12][fq] = u3; float4 v = bf2f4(u3); ACC1(v) }
    }
#pragma unroll
    for (int off = 16; off <= 32; off <<= 1) {
        mn.x = fminf(mn.x, __shfl_xor(mn.x, off)); mn.y = fminf(mn.y, __shfl_xor(mn.y, off));
        mn.z = fminf(mn.z, __shfl_xor(mn.z, off)); mn.w = fminf(mn.w, __shfl_xor(mn.w, off));
        mx.x = fmaxf(mx.x, __shfl_xor(mx.x, off)); mx.y = fmaxf(mx.y, __shfl_xor(mx.y, off));
        mx.z = fmaxf(mx.z, __shfl_xor(mx.z, off)); mx.w = fmaxf(mx.w, __shfl_xor(mx.w, off));
        sm.x += __shfl_xor(sm.x, off); sm.y += __shfl_xor(sm.y, off);
        sm.z += __shfl_xor(sm.z, off); sm.w += __shfl_xor(sm.w, off);
    }
    float4 tv = *(const float4*)(tptr + 4 * fq);
    tv.x = fminf(fmaxf(tv.x, 0.f), 1.f); tv.y = fminf(fmaxf(tv.y, 0.f), 1.f);
    tv.z = fminf(fmaxf(tv.z, 0.f), 1.f); tv.w = fminf(fmaxf(tv.w, 0.f), 1.f);
    float4 bias;
    bias.x = tv.x * mx.x + (1.f - tv.x) * mn.x;
    bias.y = tv.y * mx.y + (1.f - tv.y) * mn.y;
    bias.z = tv.z * mx.z + (1.f - tv.z) * mn.z;
    bias.w = tv.w * mx.w + (1.f - tv.w) * mn.w;
    float4 rs = make_float4(0.f, 0.f, 0.f, 0.f);

#define RACC(v) { rs.x += fmaxf(v.x - bias.x, 0.f); rs.y += fmaxf(v.y - bias.y, 0.f); \
                  rs.z += fmaxf(v.z - bias.z, 0.f); rs.w += fmaxf(v.w - bias.w, 0.f); }

    if (deg >= 16) {
#pragma unroll
        for (int i = 0; i < 4; ++i) {
            float4 v = bf2f4(cache[w][i * 4 + g][fq]);
            RACC(v)
        }
        int e = start + 16;
        for (; e + 16 <= end; e += 16) {
            int i0 = e + g;
            int s0 = srcSorted[i0], s1 = srcSorted[i0 + 4];
            int s2 = srcSorted[i0 + 8], s3 = srcSorted[i0 + 12];
            float4 v0 = bf2f4(mq[(size_t)s0 * 16]);
            float4 v1 = bf2f4(mq[(size_t)s1 * 16]);
            float4 v2 = bf2f4(mq[(size_t)s2 * 16]);
            float4 v3 = bf2f4(mq[(size_t)s3 * 16]);
            RACC(v0) RACC(v1) RACC(v2) RACC(v3)
        }
        if (e < end) {
            int i0 = e + g, i1 = i0 + 4, i2 = i0 + 8, i3 = i0 + 12;
            bool ok0 = i0 < end, ok1 = i1 < end, ok2 = i2 < end, ok3 = i3 < end;
            int s0 = 0, s1 = 0, s2 = 0, s3 = 0;
            if (ok0) s0 = srcSorted[i0];
            if (ok1) s1 = srcSorted[i1];
            if (ok2) s2 = srcSorted[i2];
            if (ok3) s3 = srcSorted[i3];
            float4 v0, v1, v2, v3;
            if (ok0) v0 = bf2f4(mq[(size_t)s0 * 16]);
            if (ok1) v1 = bf2f4(mq[(size_t)s1 * 16]);
            if (ok2) v2 = bf2f4(mq[(size_t)s2 * 16]);
            if (ok3) v3 = bf2f4(mq[(size_t)s3 * 16]);
            if (ok0) RACC(v0)
            if (ok1) RACC(v1)
            if (ok2) RACC(v2)
            if (ok3) RACC(v3)
        }
    } else {
        for (int idx = start + g; idx < end; idx += 4) {
            float4 v = bf2f4(cache[w][idx - start][fq]);
            RACC(v)
        }
    }
#pragma unroll
    for (int off = 16; off <= 32; off <<= 1) {
        rs.x += __shfl_xor(rs.x, off); rs.y += __shfl_xor(rs.y, off);
        rs.z += __shfl_xor(rs.z, off); rs.w += __shfl_xor(rs.w, off);
    }
    if (g == 0) {
        float cnt = (float)deg;
        float w0 = Wp[0], w1 = Wp[1], w2 = Wp[2], w3 = Wp[3], w4 = Wp[4], b0 = bp[0];
        float4* hp = (float4*)(hbuf + (size_t)node * 64 + 4 * fq);
        float4 h = *hp;
        h.x += w0 * cnt + w1 * mn.x + w2 * mx.x + w3 * rs.x + w4 * sm.x + b0;
        h.y += w0 * cnt + w1 * mn.y + w2 * mx.y + w3 * rs.y + w4 * sm.y + b0;
        h.z += w0 * cnt + w1 * mn.z + w2 * mx.z + w3 * rs.z + w4 * sm.z + b0;
        h.w += w0 * cnt + w1 * mn.w + w2 * mx.w + w3 * rs.w + w4 * sm.w + b0;
        *hp = h;
    }
#undef ACC1
#undef RACC
}

// ---------------- global pooling (4-phase, parallel) ----------------

__global__ __launch_bounds__(256) void gaggA_kernel(const float* __restrict__ msg,
                                                    const int* __restrict__ gstart,
                                                    float* __restrict__ pmn,
                                                    float* __restrict__ pmx,
                                                    float* __restrict__ psm) {
    const int bid = blockIdx.x;
    const int g = bid >> 4, c = bid & (GCH - 1);
    const int s = gstart[g];
    const int e = (g == G_GRAPHS - 1) ? N_NODES : gstart[g + 1];
    const int clen = (e - s + GCH - 1) / GCH;
    const int cs = s + c * clen;
    const int ce = (cs + clen < e) ? (cs + clen) : e;
    const int f = threadIdx.x & 63, r = threadIdx.x >> 6;
    float mn = __builtin_inff(), mx = -__builtin_inff(), sm = 0.f;
    for (int i = cs + r; i < ce; i += 4) {
        float v = msg[(size_t)i * 64 + f];
        mn = fminf(mn, v); mx = fmaxf(mx, v); sm += v;
    }
    __shared__ float smn[4][64], smx[4][64], ssm[4][64];
    smn[r][f] = mn; smx[r][f] = mx; ssm[r][f] = sm;
    __syncthreads();
    if (r == 0) {
        pmn[bid * 64 + f] = fminf(fminf(smn[0][f], smn[1][f]), fminf(smn[2][f], smn[3][f]));
        pmx[bid * 64 + f] = fmaxf(fmaxf(smx[0][f], smx[1][f]), fmaxf(smx[2][f], smx[3][f]));
        psm[bid * 64 + f] = ssm[0][f] + ssm[1][f] + ssm[2][f] + ssm[3][f];
    }
}

__global__ __launch_bounds__(64) void gaggB_kernel(const float* __restrict__ pmn,
                                                   const float* __restrict__ pmx,
                                                   const float* __restrict__ psm,
                                                   const float* __restrict__ gt,
                                                   float* __restrict__ gMn,
                                                   float* __restrict__ gMx,
                                                   float* __restrict__ gSm,
                                                   float* __restrict__ gBias) {
    const int g = blockIdx.x, f = threadIdx.x;
    float mn = __builtin_inff(), mx = -__builtin_inff(), sm = 0.f;
#pragma unroll
    for (int c = 0; c < GCH; ++c) {
        int i = (g * GCH + c) * 64 + f;
        mn = fminf(mn, pmn[i]); mx = fmaxf(mx, pmx[i]); sm += psm[i];
    }
    float tv = fminf(fmaxf(gt[f], 0.f), 1.f);
    gMn[g * 64 + f] = mn; gMx[g * 64 + f] = mx; gSm[g * 64 + f] = sm;
    gBias[g * 64 + f] = tv * mx + (1.f - tv) * mn;
}

__global__ __launch_bounds__(256) void gaggC_kernel(const float* __restrict__ msg,
                                                    const int* __restrict__ gstart,
                                                    const float* __restrict__ gBias,
                                                    float* __restrict__ prs) {
    const int bid = blockIdx.x;
    const int g = bid >> 4, c = bid & (GCH - 1);
    const int s = gstart[g];
    const int e = (g == G_GRAPHS - 1) ? N_NODES : gstart[g + 1];
    const int clen = (e - s + GCH - 1) / GCH;
    const int cs = s + c * clen;
    const int ce = (cs + clen < e) ? (cs + clen) : e;
    const int f = threadIdx.x & 63, r = threadIdx.x >> 6;
    const float bias = gBias[g * 64 + f];
    float rs = 0.f;
    for (int i = cs + r; i < ce; i += 4) {
        float v = msg[(size_t)i * 64 + f];
        rs += fmaxf(v - bias, 0.f);
    }
    __shared__ float srs[4][64];
    srs[r][f] = rs;
    __syncthreads();
    if (r == 0)
        prs[bid * 64 + f] = srs[0][f] + srs[1][f] + srs[2][f] + srs[3][f];
}

__global__ __launch_bounds__(64) void gaggD_kernel(const float* __restrict__ prs,
                                                   const int* __restrict__ gstart,
                                                   const float* __restrict__ gMn,
                                                   const float* __restrict__ gMx,
                                                   const float* __restrict__ gSm,
                                                   const float* __restrict__ gWp,
                                                   const float* __restrict__ gbp,
                                                   const float* __restrict__ Wout,
                                                   const float* __restrict__ bout,
                                                   float* __restrict__ out) {
    const int g = blockIdx.x, f = threadIdx.x;
    float rs = 0.f;
#pragma unroll
    for (int c = 0; c < GCH; ++c) rs += prs[(g * GCH + c) * 64 + f];
    const int s = gstart[g];
    const int e = (g == G_GRAPHS - 1) ? N_NODES : gstart[g + 1];
    float cnt = (float)(e - s);
    __shared__ float emb[64];
    emb[f] = gWp[0] * cnt + gWp[1] * gMn[g * 64 + f] + gWp[2] * gMx[g * 64 + f] +
             gWp[3] * rs + gWp[4] * gSm[g * 64 + f] + gbp[0];
    __syncthreads();
    if (f < OUTD) {
        float a = bout[f];
        const float* wr = Wout + f * 64;
#pragma unroll
        for (int k = 0; k < 64; ++k) a = fmaf(emb[k], wr[k], a);
        out[g * OUTD + f] = a;
    }
}

// ---------------- launch ----------------

extern "C" void kernel_launch(void* const* d_in, const int* in_sizes, int n_in,
                              void* d_out, int out_size, void* d_ws, size_t ws_size,
                              hipStream_t stream) {
    const float* x     = (const float*)d_in[0];
    const int*   ei    = (const int*)d_in[1];
    const int*   batch = (const int*)d_in[2];
    const float* Wlin  = (const float*)d_in[3];
    const float* blin  = (const float*)d_in[4];
    const float* t     = (const float*)d_in[5];
    const float* Wproj = (const float*)d_in[6];
    const float* bproj = (const float*)d_in[7];
    const float* Wc    = (const float*)d_in[8];
    const float* bc    = (const float*)d_in[9];
    const float* gWlin = (const float*)d_in[10];
    const float* gblin = (const float*)d_in[11];
    const float* gt    = (const float*)d_in[12];
    const float* gWproj= (const float*)d_in[13];
    const float* gbproj= (const float*)d_in[14];
    const float* Wout  = (const float*)d_in[15];
    const float* bout  = (const float*)d_in[16];
    float* out = (float*)d_out;

    const int* src = ei;
    const int* dst = ei + E_EDGES;

    // workspace layout
    char* p = (char*)d_ws;
    float* bufMsg = (float*)p; p += (size_t)N_NODES * FDIM * sizeof(float);   // f32 (global conv)
    float* bufH   = (float*)p; p += (size_t)N_NODES * FDIM * sizeof(float);
    unsigned short* msgB = (unsigned short*)p; p += (size_t)N_NODES * FDIM * sizeof(short); // bf16 layer msgs
    int* offsets  = (int*)p;   p += (size_t)(N_NODES + 1) * sizeof(int);
    int* gstart   = (int*)p;   p += (size_t)G_GRAPHS * sizeof(int);
    int* bucketStart  = (int*)p; p += (size_t)(KBUK + 1) * sizeof(int);
    int* bucketCursor = (int*)p; p += (size_t)KBUK * 16 * sizeof(int);
    int* srcSorted= (int*)p;   p += (size_t)E_EDGES * sizeof(int);
    float* pmn = (float*)p;    p += (size_t)G_GRAPHS * GCH * 64 * sizeof(float);
    float* pmx = (float*)p;    p += (size_t)G_GRAPHS * GCH * 64 * sizeof(float);
    float* psm = (float*)p;    p += (size_t)G_GRAPHS * GCH * 64 * sizeof(float);
    float* prs = (float*)p;    p += (size_t)G_GRAPHS * GCH * 64 * sizeof(float);
    float* gMn = (float*)p;    p += (size_t)G_GRAPHS * 64 * sizeof(float);
    float* gMx = (float*)p;    p += (size_t)G_GRAPHS * 64 * sizeof(float);
    float* gSm = (float*)p;    p += (size_t)G_GRAPHS * 64 * sizeof(float);
    float* gBias = (float*)p;  p += (size_t)G_GRAPHS * 64 * sizeof(float);
    int* ebuf = (int*)bufMsg;  // KBUK*CAPB ints = 8 MB; dead until last lin

    const int NB = (N_NODES + 255) / 256;
    binit_kernel<<<1, 256, 0, stream>>>(bucketCursor);
    bscatter_kernel<<<SEBLK, 256, 0, stream>>>(src, dst, bucketCursor, ebuf);
    bscan_kernel<<<1, 256, 0, stream>>>(bucketCursor, bucketStart, offsets);
    bsort_kernel<<<KBUK, 256, 0, stream>>>(ebuf, bucketStart, offsets, srcSorted);
    bound_kernel<<<NB, 256, 0, stream>>>(batch, gstart);

    const int LB = (N_NODES + 63) / 64;
    const int AB = (N_NODES + 3) / 4;

    // layer 0: msg (bf16) and combine (f32) from x
    lin_kernel<true><<<LB, 256, 0, stream>>>(x, Wlin, blin, nullptr, msgB);
    lin_kernel<false><<<LB, 256, 0, stream>>>(x, Wc, bc, bufH, nullptr);
    agg_kernel<<<AB, 256, 0, stream>>>(msgB, offsets, srcSorted, t, Wproj, bproj, bufH);
    // layer 1
    lin_kernel<true><<<LB, 256, 0, stream>>>(bufH, Wlin + 4096, blin + 64, nullptr, msgB);
    lin_kernel<false><<<LB, 256, 0, stream>>>(bufH, Wc + 4096, bc + 64, bufH, nullptr);
    agg_kernel<<<AB, 256, 0, stream>>>(msgB, offsets, srcSorted, t + 64, Wproj + 5,
                                       bproj + 1, bufH);
    // global conv message (f32)
    lin_kernel<false><<<LB, 256, 0, stream>>>(bufH, gWlin, gblin, bufMsg, nullptr);
    gaggA_kernel<<<G_GRAPHS * GCH, 256, 0, stream>>>(bufMsg, gstart, pmn, pmx, psm);
    gaggB_kernel<<<G_GRAPHS, 64, 0, stream>>>(pmn, pmx, psm, gt, gMn, gMx, gSm, gBias);
    gaggC_kernel<<<G_GRAPHS * GCH, 256, 0, stream>>>(bufMsg, gstart, gBias, prs);
    gaggD_kernel<<<G_GRAPHS, 64, 0, stream>>>(prs, gstart, gMn, gMx, gSm, gWproj,
                                              gbproj, Wout, bout, out);
}

// Round 15
// 287.845 us; speedup vs baseline: 5.9869x; 1.0655x over previous
//
#include <hip/hip_runtime.h>
#include <hip/hip_fp16.h>

#define N_NODES 100000
#define E_EDGES 1600000
#define FDIM 64
#define G_GRAPHS 128
#define OUTD 32
#define CAP 16        // edges cached in LDS per node in agg
#define NPB 512       // nodes per bucket (power of 2)
#define NPB_SH 9
#define KBUK ((N_NODES + NPB - 1) / NPB)   // 196 (<= 256)
#define CAPB 10240    // fixed edge capacity per bucket region
#define SEB 4096      // edges per block in bucket scatter
#define SEBLK ((E_EDGES + SEB - 1) / SEB)  // 391
#define GCH 16        // chunks per graph in global pooling

__device__ __forceinline__ __half2 u2h(unsigned int u) {
    union { unsigned int i; __half2 h; } c; c.i = u; return c.h;
}
__device__ __forceinline__ unsigned int h2u(__half2 h) {
    union { __half2 h; unsigned int i; } c; c.h = h; return c.i;
}
__device__ __forceinline__ __half2 sxh2(__half2 v, int off) {
    return u2h((unsigned int)__shfl_xor((int)h2u(v), off));
}
// packed f16 ops via VOP3P inline asm (ROCm fp16 header lacks __hmin2/__hmax2
// for __half2 — only the bf16 overloads exist; round-13 compile lesson)
__device__ __forceinline__ __half2 h2min(__half2 a, __half2 b) {
    unsigned int r, x = h2u(a), y = h2u(b);
    asm("v_pk_min_f16 %0, %1, %2" : "=v"(r) : "v"(x), "v"(y));
    return u2h(r);
}
__device__ __forceinline__ __half2 h2max(__half2 a, __half2 b) {
    unsigned int r, x = h2u(a), y = h2u(b);
    asm("v_pk_max_f16 %0, %1, %2" : "=v"(r) : "v"(x), "v"(y));
    return u2h(r);
}
__device__ __forceinline__ __half2 h2add(__half2 a, __half2 b) {
    unsigned int r, x = h2u(a), y = h2u(b);
    asm("v_pk_add_f16 %0, %1, %2" : "=v"(r) : "v"(x), "v"(y));
    return u2h(r);
}

// ---------------- CSR build (bucketed, fixed-capacity regions) ----------------

__global__ __launch_bounds__(256) void binit_kernel(int* __restrict__ bucketCursor) {
    int i = threadIdx.x;
    if (i < KBUK) bucketCursor[i * 16] = i * CAPB;  // line-padded counters
}

__global__ __launch_bounds__(256) void bscatter_kernel(const int* __restrict__ src,
                                                       const int* __restrict__ dst,
                                                       int* __restrict__ bucketCursor,
                                                       int* __restrict__ ebuf) {
    __shared__ int h[KBUK], resbase[KBUK], lcur[KBUK];
    for (int i = threadIdx.x; i < KBUK; i += 256) { h[i] = 0; lcur[i] = 0; }
    __syncthreads();
    const int base = blockIdx.x * SEB;
#pragma unroll
    for (int i = 0; i < 16; ++i) {
        int e = base + i * 256 + threadIdx.x;
        if (e < E_EDGES) atomicAdd(&h[dst[e] >> NPB_SH], 1);
    }
    __syncthreads();
    for (int i = threadIdx.x; i < KBUK; i += 256)
        resbase[i] = h[i] ? atomicAdd(&bucketCursor[i * 16], h[i]) : 0;
    __syncthreads();
#pragma unroll
    for (int i = 0; i < 16; ++i) {
        int e = base + i * 256 + threadIdx.x;
        if (e < E_EDGES) {
            int d = dst[e];
            int b = d >> NPB_SH;
            int pos = resbase[b] + atomicAdd(&lcur[b], 1);
            ebuf[pos] = (src[e] << NPB_SH) | (d & (NPB - 1));
        }
    }
}

__global__ __launch_bounds__(256) void bscan_kernel(const int* __restrict__ bucketCursor,
                                                    int* __restrict__ bucketStart,
                                                    int* __restrict__ offsets) {
    __shared__ int s[256];
    const int tid = threadIdx.x;
    int v = (tid < KBUK) ? (bucketCursor[tid * 16] - tid * CAPB) : 0;
    s[tid] = v;
    __syncthreads();
    for (int off = 1; off < 256; off <<= 1) {
        int t = 0;
        if (tid >= off) t = s[tid - off];
        __syncthreads();
        if (tid >= off) s[tid] += t;
        __syncthreads();
    }
    int excl = s[tid] - v;
    if (tid < KBUK) bucketStart[tid] = excl;
    if (tid == 0) { bucketStart[KBUK] = E_EDGES; offsets[N_NODES] = E_EDGES; }
}

// per-bucket counting sort -> offsets[] + srcSorted[] (prescaled by 16 = uint2-row)
__global__ __launch_bounds__(256) void bsort_kernel(const int* __restrict__ ebuf,
                                                    const int* __restrict__ bucketStart,
                                                    int* __restrict__ offsets,
                                                    int* __restrict__ srcSorted) {
    __shared__ int cnt[NPB];
    __shared__ int cur[NPB];
    __shared__ int wsum[4];
    const int b = blockIdx.x;
    const int tid = threadIdx.x;
    const int rbase = b * CAPB;
    const int ebase = bucketStart[b];
    const int cb = bucketStart[b + 1] - ebase;
    const int nbase = b * NPB;
    cnt[tid] = 0; cnt[tid + 256] = 0;
    __syncthreads();
    for (int e = tid; e < cb; e += 256)
        atomicAdd(&cnt[ebuf[rbase + e] & (NPB - 1)], 1);
    __syncthreads();
    int v0 = cnt[2 * tid], v1 = cnt[2 * tid + 1];
    int s = v0 + v1;
    const int lane = tid & 63, wv = tid >> 6;
    int incl = s;
#pragma unroll
    for (int off = 1; off < 64; off <<= 1) {
        int o = __shfl_up(incl, off);
        if (lane >= off) incl += o;
    }
    if (lane == 63) wsum[wv] = incl;
    __syncthreads();
    int wpre = 0;
#pragma unroll
    for (int w = 0; w < 4; ++w) wpre += (w < wv) ? wsum[w] : 0;
    int excl = wpre + incl - s;
    cur[2 * tid] = excl; cur[2 * tid + 1] = excl + v0;
    int n0 = nbase + 2 * tid;
    if (n0 < N_NODES) offsets[n0] = ebase + excl;
    if (n0 + 1 < N_NODES) offsets[n0 + 1] = ebase + excl + v0;
    __syncthreads();
    for (int e = tid; e < cb; e += 256) {
        int u = ebuf[rbase + e];
        int pos = ebase + atomicAdd(&cur[u & (NPB - 1)], 1);
        srcSorted[pos] = (u >> NPB_SH) << 4;  // prescaled row offset (uint2 units)
    }
}

// batch is sorted -> graph g starts where batch changes value.
__global__ __launch_bounds__(256) void bound_kernel(const int* __restrict__ batch,
                                                    int* __restrict__ gstart) {
    int i = blockIdx.x * 256 + threadIdx.x;
    if (i >= N_NODES) return;
    if (i == 0) {
        gstart[batch[0]] = 0;
    } else {
        int b = batch[i], pb = batch[i - 1];
        if (b != pb) gstart[b] = i;
    }
}

// ---------------- linear: out = in@W.T + b  (4x4 register-tiled) ----------------
// F16OUT=true stores f16 (message tables), else f32 (combine / h).
// #pragma unroll 2 caps load hoisting (round-10 spill lesson).
// In-place safe (outF == in): block stages its own 64 rows before the barrier.

template <bool F16OUT>
__global__ __launch_bounds__(256) void lin_kernel(const float* __restrict__ in,
                                                  const float* __restrict__ W,
                                                  const float* __restrict__ b,
                                                  float* __restrict__ outF,
                                                  __half* __restrict__ outH) {
    __shared__ __align__(16) float4 shH[1024];  // 16 KB
    __shared__ __align__(16) float4 shW[1024];  // 16 KB
    const int tid = threadIdx.x;
    const int base = blockIdx.x * 64;
#pragma unroll
    for (int i = 0; i < 4; ++i) {
        int j = tid + i * 256;                 // float4 index in 64x64 tile
        int row = j >> 4, col = j & 15;
        int swz = row * 16 + (col ^ ((row >> 2) & 7));
        if (base + row < N_NODES)
            shH[swz] = ((const float4*)in)[(size_t)base * 16 + j];
        shW[swz] = ((const float4*)W)[j];
    }
    __syncthreads();
    const int fj = tid & 15, ni = tid >> 4;
    float acc[4][4] = {{0}};
    const int hs = ni & 7;
    const int ws = fj & 7;
#pragma unroll 2
    for (int kk = 0; kk < 16; ++kk) {
        const int hk = kk ^ hs, wk = kk ^ ws;
        float4 h0 = shH[(4 * ni + 0) * 16 + hk];
        float4 h1 = shH[(4 * ni + 1) * 16 + hk];
        float4 h2 = shH[(4 * ni + 2) * 16 + hk];
        float4 h3 = shH[(4 * ni + 3) * 16 + hk];
#pragma unroll
        for (int j = 0; j < 4; ++j) {
            float4 wv = shW[(4 * fj + j) * 16 + wk];
            acc[0][j] += h0.x * wv.x + h0.y * wv.y + h0.z * wv.z + h0.w * wv.w;
            acc[1][j] += h1.x * wv.x + h1.y * wv.y + h1.z * wv.z + h1.w * wv.w;
            acc[2][j] += h2.x * wv.x + h2.y * wv.y + h2.z * wv.z + h2.w * wv.w;
            acc[3][j] += h3.x * wv.x + h3.y * wv.y + h3.z * wv.z + h3.w * wv.w;
        }
    }
    float4 b4 = *(const float4*)(b + 4 * fj);
#pragma unroll
    for (int r = 0; r < 4; ++r) {
        int node = base + 4 * ni + r;
        if (node < N_NODES) {
            if (F16OUT) {
                uint2 st;
                st.x = h2u(__floats2half2_rn(acc[r][0] + b4.x, acc[r][1] + b4.y));
                st.y = h2u(__floats2half2_rn(acc[r][2] + b4.z, acc[r][3] + b4.w));
                *(uint2*)(outH + (size_t)node * 64 + 4 * fj) = st;
            } else {
                float4 o = make_float4(acc[r][0] + b4.x, acc[r][1] + b4.y,
                                       acc[r][2] + b4.z, acc[r][3] + b4.w);
                *(float4*)(outF + (size_t)node * 64 + 4 * fj) = o;
            }
        }
    }
}

// ---------------- per-node adaptive-relu aggregation (packed f16) ----------------
// wave per node; lane = (edge group g = lane>>4, feature quad fq = lane&15).
// Row = 64 f16 = 128 B; lane loads uint2 (2x half2). All min/max/sum in packed
// f16. Relu pass uses max(v-b,0) = max(v,b) - b: accumulate Σmax(v,bias) in
// f16 (2 ops/half2), subtract deg*bias once in f32.

__global__ __launch_bounds__(256) void agg_kernel(const __half* __restrict__ msgH,
                                                  const int* __restrict__ offsets,
                                                  const int* __restrict__ srcSorted,
                                                  const float* __restrict__ tptr,
                                                  const float* __restrict__ Wp,
                                                  const float* __restrict__ bp,
                                                  float* __restrict__ hbuf) {
    __shared__ uint2 cache[4][CAP][16];  // 8 KB
    const int w = threadIdx.x >> 6;
    const int lane = threadIdx.x & 63;
    const int g = lane >> 4;
    const int fq = lane & 15;
    const int node = blockIdx.x * 4 + w;
    if (node >= N_NODES) return;
    const int start = offsets[node], end = offsets[node + 1];
    const int deg = end - start;
    const uint2* mq = (const uint2*)msgH + fq;  // row stride = 16 uint2 (128 B)
    const float INF = 65504.f;  // f16 max
    __half2 mnA = __float2half2_rn(INF),  mnB = __float2half2_rn(INF);
    __half2 mxA = __float2half2_rn(-INF), mxB = __float2half2_rn(-INF);
    __half2 smA = __float2half2_rn(0.f),  smB = __float2half2_rn(0.f);

#define ACCU(u) { __half2 a_ = u2h((u).x), b_ = u2h((u).y); \
    mnA = h2min(mnA, a_); mxA = h2max(mxA, a_); smA = h2add(smA, a_); \
    mnB = h2min(mnB, b_); mxB = h2max(mxB, b_); smB = h2add(smB, b_); }

    if (deg >= 16) {
        {
            int i0 = start + g;
            int s0 = srcSorted[i0], s1 = srcSorted[i0 + 4];
            int s2 = srcSorted[i0 + 8], s3 = srcSorted[i0 + 12];
            uint2 u0 = mq[(size_t)s0], u1 = mq[(size_t)s1];
            uint2 u2 = mq[(size_t)s2], u3 = mq[(size_t)s3];
            cache[w][g][fq] = u0; cache[w][g + 4][fq] = u1;
            cache[w][g + 8][fq] = u2; cache[w][g + 12][fq] = u3;
            ACCU(u0) ACCU(u1) ACCU(u2) ACCU(u3)
        }
        int e = start + 16;
        for (; e + 16 <= end; e += 16) {
            int i0 = e + g;
            int s0 = srcSorted[i0], s1 = srcSorted[i0 + 4];
            int s2 = srcSorted[i0 + 8], s3 = srcSorted[i0 + 12];
            uint2 u0 = mq[(size_t)s0], u1 = mq[(size_t)s1];
            uint2 u2 = mq[(size_t)s2], u3 = mq[(size_t)s3];
            ACCU(u0) ACCU(u1) ACCU(u2) ACCU(u3)
        }
        if (e < end) {
            int i0 = e + g, i1 = i0 + 4, i2 = i0 + 8, i3 = i0 + 12;
            bool ok0 = i0 < end, ok1 = i1 < end, ok2 = i2 < end, ok3 = i3 < end;
            int s0 = 0, s1 = 0, s2 = 0, s3 = 0;
            if (ok0) s0 = srcSorted[i0];
            if (ok1) s1 = srcSorted[i1];
            if (ok2) s2 = srcSorted[i2];
            if (ok3) s3 = srcSorted[i3];
            uint2 u0, u1, u2, u3;
            if (ok0) u0 = mq[(size_t)s0];
            if (ok1) u1 = mq[(size_t)s1];
            if (ok2) u2 = mq[(size_t)s2];
            if (ok3) u3 = mq[(size_t)s3];
            if (ok0) ACCU(u0)
            if (ok1) ACCU(u1)
            if (ok2) ACCU(u2)
            if (ok3) ACCU(u3)
        }
    } else {
        int i0 = start + g, i1 = i0 + 4, i2 = i0 + 8, i3 = i0 + 12;
        bool ok0 = i0 < end, ok1 = i1 < end, ok2 = i2 < end, ok3 = i3 < end;
        int s0 = 0, s1 = 0, s2 = 0, s3 = 0;
        if (ok0) s0 = srcSorted[i0];
        if (ok1) s1 = srcSorted[i1];
        if (ok2) s2 = srcSorted[i2];
        if (ok3) s3 = srcSorted[i3];
        uint2 u0, u1, u2, u3;
        if (ok0) u0 = mq[(size_t)s0];
        if (ok1) u1 = mq[(size_t)s1];
        if (ok2) u2 = mq[(size_t)s2];
        if (ok3) u3 = mq[(size_t)s3];
        if (ok0) { cache[w][g][fq] = u0;      ACCU(u0) }
        if (ok1) { cache[w][g + 4][fq] = u1;  ACCU(u1) }
        if (ok2) { cache[w][g + 8][fq] = u2;  ACCU(u2) }
        if (ok3) { cache[w][g + 12][fq] = u3; ACCU(u3) }
    }
#pragma unroll
    for (int off = 16; off <= 32; off <<= 1) {
        mnA = h2min(mnA, sxh2(mnA, off)); mnB = h2min(mnB, sxh2(mnB, off));
        mxA = h2max(mxA, sxh2(mxA, off)); mxB = h2max(mxB, sxh2(mxB, off));
        smA = h2add(smA, sxh2(smA, off)); smB = h2add(smB, sxh2(smB, off));
    }
    // unpack stats, compute bias in f32, repack
    float mn0 = __low2float(mnA), mn1 = __high2float(mnA);
    float mn2 = __low2float(mnB), mn3 = __high2float(mnB);
    float mx0 = __low2float(mxA), mx1 = __high2float(mxA);
    float mx2 = __low2float(mxB), mx3 = __high2float(mxB);
    float4 tv = *(const float4*)(tptr + 4 * fq);
    tv.x = fminf(fmaxf(tv.x, 0.f), 1.f); tv.y = fminf(fmaxf(tv.y, 0.f), 1.f);
    tv.z = fminf(fmaxf(tv.z, 0.f), 1.f); tv.w = fminf(fmaxf(tv.w, 0.f), 1.f);
    float b0 = tv.x * mx0 + (1.f - tv.x) * mn0;
    float b1 = tv.y * mx1 + (1.f - tv.y) * mn1;
    float b2 = tv.z * mx2 + (1.f - tv.z) * mn2;
    float b3 = tv.w * mx3 + (1.f - tv.w) * mn3;
    __half2 biasA = __floats2half2_rn(b0, b1);
    __half2 biasB = __floats2half2_rn(b2, b3);
    // use bias as actually representable in f16 for the subtraction
    float fb0 = __low2float(biasA), fb1 = __high2float(biasA);
    float fb2 = __low2float(biasB), fb3 = __high2float(biasB);
    __half2 rsA = __float2half2_rn(0.f), rsB = __float2half2_rn(0.f);

#define RACCU(u) { __half2 a_ = u2h((u).x), b_ = u2h((u).y); \
    rsA = h2add(rsA, h2max(a_, biasA)); \
    rsB = h2add(rsB, h2max(b_, biasB)); }

    if (deg >= 16) {
#pragma unroll
        for (int i = 0; i < 4; ++i) {
            uint2 u = cache[w][i * 4 + g][fq];
            RACCU(u)
        }
        int e = start + 16;
        for (; e + 16 <= end; e += 16) {
            int i0 = e + g;
            int s0 = srcSorted[i0], s1 = srcSorted[i0 + 4];
            int s2 = srcSorted[i0 + 8], s3 = srcSorted[i0 + 12];
            uint2 u0 = mq[(size_t)s0], u1 = mq[(size_t)s1];
            uint2 u2 = mq[(size_t)s2], u3 = mq[(size_t)s3];
            RACCU(u0) RACCU(u1) RACCU(u2) RACCU(u3)
        }
        if (e < end) {
            int i0 = e + g, i1 = i0 + 4, i2 = i0 + 8, i3 = i0 + 12;
            bool ok0 = i0 < end, ok1 = i1 < end, ok2 = i2 < end, ok3 = i3 < end;
            int s0 = 0, s1 = 0, s2 = 0, s3 = 0;
            if (ok0) s0 = srcSorted[i0];
            if (ok1) s1 = srcSorted[i1];
            if (ok2) s2 = srcSorted[i2];
            if (ok3) s3 = srcSorted[i3];
            uint2 u0, u1, u2, u3;
            if (ok0) u0 = mq[(size_t)s0];
            if (ok1) u1 = mq[(size_t)s1];
            if (ok2) u2 = mq[(size_t)s2];
            if (ok3) u3 = mq[(size_t)s3];
            if (ok0) RACCU(u0)
            if (ok1) RACCU(u1)
            if (ok2) RACCU(u2)
            if (ok3) RACCU(u3)
        }
    } else {
        for (int idx = start + g; idx < end; idx += 4) {
            uint2 u = cache[w][idx - start][fq];
            RACCU(u)
        }
    }
#pragma unroll
    for (int off = 16; off <= 32; off <<= 1) {
        rsA = h2add(rsA, sxh2(rsA, off));
        rsB = h2add(rsB, sxh2(rsB, off));
    }
    if (g == 0) {
        float cnt = (float)deg;
        float w0 = Wp[0], w1 = Wp[1], w2 = Wp[2], w3 = Wp[3], w4 = Wp[4], bp0 = bp[0];
        // rs = Σ max(v, bias) - deg * bias   (bias at f16 precision)
        float rs0 = __low2float(rsA) - cnt * fb0;
        float rs1 = __high2float(rsA) - cnt * fb1;
        float rs2 = __low2float(rsB) - cnt * fb2;
        float rs3 = __high2float(rsB) - cnt * fb3;
        float sm0 = __low2float(smA), sm1 = __high2float(smA);
        float sm2 = __low2float(smB), sm3 = __high2float(smB);
        float4* hp = (float4*)(hbuf + (size_t)node * 64 + 4 * fq);
        float4 h = *hp;
        h.x += w0 * cnt + w1 * mn0 + w2 * mx0 + w3 * rs0 + w4 * sm0 + bp0;
        h.y += w0 * cnt + w1 * mn1 + w2 * mx1 + w3 * rs1 + w4 * sm1 + bp0;
        h.z += w0 * cnt + w1 * mn2 + w2 * mx2 + w3 * rs2 + w4 * sm2 + bp0;
        h.w += w0 * cnt + w1 * mn3 + w2 * mx3 + w3 * rs3 + w4 * sm3 + bp0;
        *hp = h;
    }
#undef ACCU
#undef RACCU
}

// ---------------- global pooling (4-phase, parallel; f16 input) ----------------

__global__ __launch_bounds__(256) void gaggA_kernel(const __half* __restrict__ msgH,
                                                    const int* __restrict__ gstart,
                                                    float* __restrict__ pmn,
                                                    float* __restrict__ pmx,
                                                    float* __restrict__ psm) {
    const int bid = blockIdx.x;
    const int g = bid >> 4, c = bid & (GCH - 1);
    const int s = gstart[g];
    const int e = (g == G_GRAPHS - 1) ? N_NODES : gstart[g + 1];
    const int clen = (e - s + GCH - 1) / GCH;
    const int cs = s + c * clen;
    const int ce = (cs + clen < e) ? (cs + clen) : e;
    const int f = threadIdx.x & 63, r = threadIdx.x >> 6;
    float mn = __builtin_inff(), mx = -__builtin_inff(), sm = 0.f;
    for (int i = cs + r; i < ce; i += 4) {
        float v = __half2float(msgH[(size_t)i * 64 + f]);
        mn = fminf(mn, v); mx = fmaxf(mx, v); sm += v;
    }
    __shared__ float smn[4][64], smx[4][64], ssm[4][64];
    smn[r][f] = mn; smx[r][f] = mx; ssm[r][f] = sm;
    __syncthreads();
    if (r == 0) {
        pmn[bid * 64 + f] = fminf(fminf(smn[0][f], smn[1][f]), fminf(smn[2][f], smn[3][f]));
        pmx[bid * 64 + f] = fmaxf(fmaxf(smx[0][f], smx[1][f]), fmaxf(smx[2][f], smx[3][f]));
        psm[bid * 64 + f] = ssm[0][f] + ssm[1][f] + ssm[2][f] + ssm[3][f];
    }
}

__global__ __launch_bounds__(64) void gaggB_kernel(const float* __restrict__ pmn,
                                                   const float* __restrict__ pmx,
                                                   const float* __restrict__ psm,
                                                   const float* __restrict__ gt,
                                                   float* __restrict__ gMn,
                                                   float* __restrict__ gMx,
                                                   float* __restrict__ gSm,
                                                   float* __restrict__ gBias) {
    const int g = blockIdx.x, f = threadIdx.x;
    float mn = __builtin_inff(), mx = -__builtin_inff(), sm = 0.f;
#pragma unroll
    for (int c = 0; c < GCH; ++c) {
        int i = (g * GCH + c) * 64 + f;
        mn = fminf(mn, pmn[i]); mx = fmaxf(mx, pmx[i]); sm += psm[i];
    }
    float tv = fminf(fmaxf(gt[f], 0.f), 1.f);
    gMn[g * 64 + f] = mn; gMx[g * 64 + f] = mx; gSm[g * 64 + f] = sm;
    gBias[g * 64 + f] = tv * mx + (1.f - tv) * mn;
}

__global__ __launch_bounds__(256) void gaggC_kernel(const __half* __restrict__ msgH,
                                                    const int* __restrict__ gstart,
                                                    const float* __restrict__ gBias,
                                                    float* __restrict__ prs) {
    const int bid = blockIdx.x;
    const int g = bid >> 4, c = bid & (GCH - 1);
    const int s = gstart[g];
    const int e = (g == G_GRAPHS - 1) ? N_NODES : gstart[g + 1];
    const int clen = (e - s + GCH - 1) / GCH;
    const int cs = s + c * clen;
    const int ce = (cs + clen < e) ? (cs + clen) : e;
    const int f = threadIdx.x & 63, r = threadIdx.x >> 6;
    const float bias = gBias[g * 64 + f];
    float rs = 0.f;
    for (int i = cs + r; i < ce; i += 4) {
        float v = __half2float(msgH[(size_t)i * 64 + f]);
        rs += fmaxf(v - bias, 0.f);
    }
    __shared__ float srs[4][64];
    srs[r][f] = rs;
    __syncthreads();
    if (r == 0)
        prs[bid * 64 + f] = srs[0][f] + srs[1][f] + srs[2][f] + srs[3][f];
}

__global__ __launch_bounds__(64) void gaggD_kernel(const float* __restrict__ prs,
                                                   const int* __restrict__ gstart,
                                                   const float* __restrict__ gMn,
                                                   const float* __restrict__ gMx,
                                                   const float* __restrict__ gSm,
                                                   const float* __restrict__ gWp,
                                                   const float* __restrict__ gbp,
                                                   const float* __restrict__ Wout,
                                                   const float* __restrict__ bout,
                                                   float* __restrict__ out) {
    const int g = blockIdx.x, f = threadIdx.x;
    float rs = 0.f;
#pragma unroll
    for (int c = 0; c < GCH; ++c) rs += prs[(g * GCH + c) * 64 + f];
    const int s = gstart[g];
    const int e = (g == G_GRAPHS - 1) ? N_NODES : gstart[g + 1];
    float cnt = (float)(e - s);
    __shared__ float emb[64];
    emb[f] = gWp[0] * cnt + gWp[1] * gMn[g * 64 + f] + gWp[2] * gMx[g * 64 + f] +
             gWp[3] * rs + gWp[4] * gSm[g * 64 + f] + gbp[0];
    __syncthreads();
    if (f < OUTD) {
        float a = bout[f];
        const float* wr = Wout + f * 64;
#pragma unroll
        for (int k = 0; k < 64; ++k) a = fmaf(emb[k], wr[k], a);
        out[g * OUTD + f] = a;
    }
}

// ---------------- launch ----------------

extern "C" void kernel_launch(void* const* d_in, const int* in_sizes, int n_in,
                              void* d_out, int out_size, void* d_ws, size_t ws_size,
                              hipStream_t stream) {
    const float* x     = (const float*)d_in[0];
    const int*   ei    = (const int*)d_in[1];
    const int*   batch = (const int*)d_in[2];
    const float* Wlin  = (const float*)d_in[3];
    const float* blin  = (const float*)d_in[4];
    const float* t     = (const float*)d_in[5];
    const float* Wproj = (const float*)d_in[6];
    const float* bproj = (const float*)d_in[7];
    const float* Wc    = (const float*)d_in[8];
    const float* bc    = (const float*)d_in[9];
    const float* gWlin = (const float*)d_in[10];
    const float* gblin = (const float*)d_in[11];
    const float* gt    = (const float*)d_in[12];
    const float* gWproj= (const float*)d_in[13];
    const float* gbproj= (const float*)d_in[14];
    const float* Wout  = (const float*)d_in[15];
    const float* bout  = (const float*)d_in[16];
    float* out = (float*)d_out;

    const int* src = ei;
    const int* dst = ei + E_EDGES;

    // workspace layout
    char* p = (char*)d_ws;
    float* bufH   = (float*)p; p += (size_t)N_NODES * FDIM * sizeof(float);
    __half* msgH  = (__half*)p; p += (size_t)N_NODES * FDIM * sizeof(__half);
    int* ebuf     = (int*)p;   p += (size_t)KBUK * CAPB * sizeof(int);
    int* offsets  = (int*)p;   p += (size_t)(N_NODES + 1) * sizeof(int);
    int* gstart   = (int*)p;   p += (size_t)G_GRAPHS * sizeof(int);
    int* bucketStart  = (int*)p; p += (size_t)(KBUK + 1) * sizeof(int);
    int* bucketCursor = (int*)p; p += (size_t)KBUK * 16 * sizeof(int);
    int* srcSorted= (int*)p;   p += (size_t)E_EDGES * sizeof(int);
    float* pmn = (float*)p;    p += (size_t)G_GRAPHS * GCH * 64 * sizeof(float);
    float* pmx = (float*)p;    p += (size_t)G_GRAPHS * GCH * 64 * sizeof(float);
    float* psm = (float*)p;    p += (size_t)G_GRAPHS * GCH * 64 * sizeof(float);
    float* prs = (float*)p;    p += (size_t)G_GRAPHS * GCH * 64 * sizeof(float);
    float* gMn = (float*)p;    p += (size_t)G_GRAPHS * 64 * sizeof(float);
    float* gMx = (float*)p;    p += (size_t)G_GRAPHS * 64 * sizeof(float);
    float* gSm = (float*)p;    p += (size_t)G_GRAPHS * 64 * sizeof(float);
    float* gBias = (float*)p;  p += (size_t)G_GRAPHS * 64 * sizeof(float);

    const int NB = (N_NODES + 255) / 256;
    binit_kernel<<<1, 256, 0, stream>>>(bucketCursor);
    bscatter_kernel<<<SEBLK, 256, 0, stream>>>(src, dst, bucketCursor, ebuf);
    bscan_kernel<<<1, 256, 0, stream>>>(bucketCursor, bucketStart, offsets);
    bsort_kernel<<<KBUK, 256, 0, stream>>>(ebuf, bucketStart, offsets, srcSorted);
    bound_kernel<<<NB, 256, 0, stream>>>(batch, gstart);

    const int LB = (N_NODES + 63) / 64;
    const int AB = (N_NODES + 3) / 4;

    // layer 0: msg (f16) and combine (f32) from x
    lin_kernel<true><<<LB, 256, 0, stream>>>(x, Wlin, blin, nullptr, msgH);
    lin_kernel<false><<<LB, 256, 0, stream>>>(x, Wc, bc, bufH, nullptr);
    agg_kernel<<<AB, 256, 0, stream>>>(msgH, offsets, srcSorted, t, Wproj, bproj, bufH);
    // layer 1
    lin_kernel<true><<<LB, 256, 0, stream>>>(bufH, Wlin + 4096, blin + 64, nullptr, msgH);
    lin_kernel<false><<<LB, 256, 0, stream>>>(bufH, Wc + 4096, bc + 64, bufH, nullptr);
    agg_kernel<<<AB, 256, 0, stream>>>(msgH, offsets, srcSorted, t + 64, Wproj + 5,
                                       bproj + 1, bufH);
    // global conv message (f16)
    lin_kernel<true><<<LB, 256, 0, stream>>>(bufH, gWlin, gblin, nullptr, msgH);
    gaggA_kernel<<<G_GRAPHS * GCH, 256, 0, stream>>>(msgH, gstart, pmn, pmx, psm);
    gaggB_kernel<<<G_GRAPHS, 64, 0, stream>>>(pmn, pmx, psm, gt, gMn, gMx, gSm, gBias);
    gaggC_kernel<<<G_GRAPHS * GCH, 256, 0, stream>>>(msgH, gstart, gBias, prs);
    gaggD_kernel<<<G_GRAPHS, 64, 0, stream>>>(prs, gstart, gMn, gMx, gSm, gWproj,
                                              gbproj, Wout, bout, out);
}